// Round 2
// baseline (354.102 us; speedup 1.0000x reference)
//
#include <hip/hip_runtime.h>
#include <cstdint>

#define NTOK 2048
#define DIM 512
#define EDIM 2048
#define BATCH 4
#define HEADS 8
#define BNROWS 8192   /* B*N */
#define INV_N (1.0f/2048.0f)

typedef unsigned short u16;
typedef __bf16 bf16x8 __attribute__((ext_vector_type(8)));
typedef u16   u16x8  __attribute__((ext_vector_type(8)));
typedef float f32x4  __attribute__((ext_vector_type(4)));

__device__ __forceinline__ u16 f2bf(float f) {
  union { float f; uint32_t u; } v; v.f = f;
  uint32_t r = v.u + 0x7FFFu + ((v.u >> 16) & 1u);   // RNE
  return (u16)(r >> 16);
}
__device__ __forceinline__ float bf2f(u16 b) {
  union { uint32_t u; float f; } v; v.u = ((uint32_t)b) << 16;
  return v.f;
}
__device__ __forceinline__ bf16x8 ldb(const u16* p) {
  u16x8 r = *(const u16x8*)p;
  return __builtin_bit_cast(bf16x8, r);
}
#define MFMA16(a,b,c) __builtin_amdgcn_mfma_f32_16x16x32_bf16((a),(b),(c),0,0,0)

__device__ __forceinline__ float silu_f(float s) {
  return s / (1.0f + __expf(-s));
}

// ---------------- cast / transpose weights ----------------
// uvqk: f32 [512][2048] -> bf16 [2048][512] (transposed)
__global__ __launch_bounds__(256) void k_cast_uvqk(const float* __restrict__ in,
                                                   u16* __restrict__ out) {
  __shared__ float tile[32][33];
  int tx = threadIdx.x & 31, ty = threadIdx.x >> 5;
  int j0 = blockIdx.x * 32;   // col in input (0..2047)
  int k0 = blockIdx.y * 32;   // row in input (0..511)
#pragma unroll
  for (int r = ty; r < 32; r += 8)
    tile[r][tx] = in[(size_t)(k0 + r) * EDIM + j0 + tx];
  __syncthreads();
#pragma unroll
  for (int r = ty; r < 32; r += 8)
    out[(size_t)(j0 + r) * DIM + k0 + tx] = f2bf(tile[tx][r]);
}

// o_w: f32 [512][512] -> bf16 [512][512] (same layout, [out_d][in_f])
__global__ __launch_bounds__(256) void k_cast_ow(const float* __restrict__ in,
                                                 u16* __restrict__ out) {
  int i = blockIdx.x * 256 + threadIdx.x;
  out[i] = f2bf(in[i]);
}

// ---------------- LayerNorm(x) -> bf16 ----------------
__global__ __launch_bounds__(256) void k_ln1(const float* __restrict__ x,
                                             u16* __restrict__ xn) {
  int lane = threadIdx.x & 63, wid = threadIdx.x >> 6;
  size_t row = (size_t)blockIdx.x * 4 + wid;
  const float* xr = x + row * DIM;
  float4 a = ((const float4*)xr)[lane * 2];
  float4 b = ((const float4*)xr)[lane * 2 + 1];
  float s = a.x + a.y + a.z + a.w + b.x + b.y + b.z + b.w;
#pragma unroll
  for (int o = 32; o; o >>= 1) s += __shfl_xor(s, o);
  float mu = s * (1.0f / DIM);
  float d[8] = {a.x - mu, a.y - mu, a.z - mu, a.w - mu,
                b.x - mu, b.y - mu, b.z - mu, b.w - mu};
  float v = 0.f;
#pragma unroll
  for (int j = 0; j < 8; ++j) v += d[j] * d[j];
#pragma unroll
  for (int o = 32; o; o >>= 1) v += __shfl_xor(v, o);
  float rs = rsqrtf(v * (1.0f / DIM) + 1e-6f);
  u16x8 o8;
#pragma unroll
  for (int j = 0; j < 8; ++j) o8[j] = f2bf(d[j] * rs);
  *(u16x8*)(xn + row * DIM + lane * 8) = o8;
}

// ---------------- GEMM1: proj = silu(xn @ uvqk) ----------------
// A: bf16 [8192][512]; Bt: bf16 [2048][512] (col-major of uvqk); P: bf16 [8192][2048]
__global__ __launch_bounds__(256) void k_gemm1(const u16* __restrict__ A,
                                               const u16* __restrict__ Bt,
                                               u16* __restrict__ P) {
  int lane = threadIdx.x & 63, wid = threadIdx.x >> 6;
  int lm = lane & 15, lg = lane >> 4;
  int r0 = blockIdx.y * 64 + wid * 16;
  int c0 = blockIdx.x * 64;
  const u16* ap = A + (size_t)(r0 + lm) * DIM + lg * 8;
  const u16* bp = Bt + (size_t)(c0 + lm) * DIM + lg * 8;
  f32x4 acc[4];
  f32x4 z = {0.f, 0.f, 0.f, 0.f};
#pragma unroll
  for (int jt = 0; jt < 4; ++jt) acc[jt] = z;
#pragma unroll 4
  for (int k0 = 0; k0 < DIM; k0 += 32) {
    bf16x8 af = ldb(ap + k0);
#pragma unroll
    for (int jt = 0; jt < 4; ++jt)
      acc[jt] = MFMA16(af, ldb(bp + (size_t)jt * 16 * DIM + k0), acc[jt]);
  }
#pragma unroll
  for (int jt = 0; jt < 4; ++jt)
#pragma unroll
    for (int i = 0; i < 4; ++i) {
      size_t row = r0 + lg * 4 + i;
      int col = c0 + jt * 16 + lm;
      P[row * EDIM + col] = f2bf(silu_f(acc[jt][i]));
    }
}

// ---------------- HSTU attention ----------------
// proj bf16 [8192][2048]: u[0:512] v[512:1024] q[1024:1536] k[1536:2048]
// attn f32 [8192][512]
__global__ __launch_bounds__(256) void k_attn(const u16* __restrict__ proj,
                                              float* __restrict__ attn) {
  __shared__ u16 k_lds[32][72];       // K tile: [m 32][d 64] + 8 pad
  __shared__ u16 v_lds[64][40];       // V^T : [e 64][m 32] + 8 pad
  __shared__ u16 p_lds[4][16][40];    // per-wave P: [q 16][m 32] + 8 pad
  int tid = threadIdx.x;
  int lane = tid & 63, wid = tid >> 6;
  int lm = lane & 15, lg = lane >> 4;
  int n0 = blockIdx.x * 64;
  int bh = blockIdx.y;
  int b = bh >> 3, h = bh & 7;
  const u16* pb = proj + (size_t)b * NTOK * EDIM;
  int nw = n0 + wid * 16;

  const u16* qrow = pb + (size_t)(nw + lm) * EDIM + 1024 + h * 64 + lg * 8;
  bf16x8 qf0 = ldb(qrow);
  bf16x8 qf1 = ldb(qrow + 32);

  f32x4 z = {0.f, 0.f, 0.f, 0.f};
  f32x4 acc[4];
#pragma unroll
  for (int i = 0; i < 4; ++i) acc[i] = z;

  int mr = tid >> 3, d0 = (tid & 7) << 3;
  const u16* krow0 = pb + (size_t)mr * EDIM + 1536 + h * 64 + d0;
  const u16* vrow0 = pb + (size_t)mr * EDIM + 512 + h * 64 + d0;

  for (int m0 = 0; m0 < n0 + 64; m0 += 32) {
    // ---- stage K tile and V^T tile ----
    u16x8 kv = *(const u16x8*)(krow0 + (size_t)m0 * EDIM);
    u16x8 vv = *(const u16x8*)(vrow0 + (size_t)m0 * EDIM);
    *(u16x8*)&k_lds[mr][d0] = kv;
#pragma unroll
    for (int j = 0; j < 8; ++j) v_lds[d0 + j][mr] = vv[j];
    __syncthreads();

    if (m0 <= nw + 15) {   // wave-level causal skip
      f32x4 s0 = z, s1 = z;
      s0 = MFMA16(qf0, ldb(&k_lds[lm][lg * 8]), s0);
      s0 = MFMA16(qf1, ldb(&k_lds[lm][32 + lg * 8]), s0);
      s1 = MFMA16(qf0, ldb(&k_lds[16 + lm][lg * 8]), s1);
      s1 = MFMA16(qf1, ldb(&k_lds[16 + lm][32 + lg * 8]), s1);
#pragma unroll
      for (int i = 0; i < 4; ++i) {
        int n = nw + lg * 4 + i;
        int ma = m0 + lm, mb = m0 + 16 + lm;
        float pa = s0[i], pbv = s1[i];
        pa  = (ma <= n) ? silu_f(pa) * INV_N : 0.f;
        pbv = (mb <= n) ? silu_f(pbv) * INV_N : 0.f;
        p_lds[wid][lg * 4 + i][lm] = f2bf(pa);
        p_lds[wid][lg * 4 + i][16 + lm] = f2bf(pbv);
      }
      bf16x8 pf = ldb(&p_lds[wid][lm][lg * 8]);
#pragma unroll
      for (int et = 0; et < 4; ++et)
        acc[et] = MFMA16(pf, ldb(&v_lds[et * 16 + lm][lg * 8]), acc[et]);
    }
    __syncthreads();
  }

#pragma unroll
  for (int et = 0; et < 4; ++et)
#pragma unroll
    for (int i = 0; i < 4; ++i)
      attn[((size_t)b * NTOK + nw + lg * 4 + i) * DIM + h * 64 + et * 16 + lm] =
          acc[et][i];
}

// ---------------- LN(attn) * u -> bf16 ----------------
__global__ __launch_bounds__(256) void k_ln2(const float* __restrict__ attn,
                                             const u16* __restrict__ proj,
                                             u16* __restrict__ o_in) {
  int lane = threadIdx.x & 63, wid = threadIdx.x >> 6;
  size_t row = (size_t)blockIdx.x * 4 + wid;
  const float* ar = attn + row * DIM;
  float4 a = ((const float4*)ar)[lane * 2];
  float4 b = ((const float4*)ar)[lane * 2 + 1];
  float s = a.x + a.y + a.z + a.w + b.x + b.y + b.z + b.w;
#pragma unroll
  for (int o = 32; o; o >>= 1) s += __shfl_xor(s, o);
  float mu = s * (1.0f / DIM);
  float d[8] = {a.x - mu, a.y - mu, a.z - mu, a.w - mu,
                b.x - mu, b.y - mu, b.z - mu, b.w - mu};
  float v = 0.f;
#pragma unroll
  for (int j = 0; j < 8; ++j) v += d[j] * d[j];
#pragma unroll
  for (int o = 32; o; o >>= 1) v += __shfl_xor(v, o);
  float rs = rsqrtf(v * (1.0f / DIM) + 1e-6f);
  u16x8 u8 = *(const u16x8*)(proj + row * EDIM + lane * 8);  // u slice, already silu'd
  u16x8 o8;
#pragma unroll
  for (int j = 0; j < 8; ++j) o8[j] = f2bf(bf2f(u8[j]) * (d[j] * rs));
  *(u16x8*)(o_in + row * DIM + lane * 8) = o8;
}

// ---------------- GEMM2: out = o_in @ o_w^T + o_b + x ----------------
// A: bf16 [8192][512]; Bw: bf16 [512][512] ([d][f] = [j][k]); out f32 [8192][512]
__global__ __launch_bounds__(256) void k_gemm2(const u16* __restrict__ A,
                                               const u16* __restrict__ Bw,
                                               const float* __restrict__ o_b,
                                               const float* __restrict__ x,
                                               float* __restrict__ out) {
  int lane = threadIdx.x & 63, wid = threadIdx.x >> 6;
  int lm = lane & 15, lg = lane >> 4;
  int r0 = blockIdx.y * 64 + wid * 16;
  int c0 = blockIdx.x * 64;
  const u16* ap = A + (size_t)(r0 + lm) * DIM + lg * 8;
  const u16* bp = Bw + (size_t)(c0 + lm) * DIM + lg * 8;
  f32x4 acc[4];
  f32x4 z = {0.f, 0.f, 0.f, 0.f};
#pragma unroll
  for (int jt = 0; jt < 4; ++jt) acc[jt] = z;
#pragma unroll 4
  for (int k0 = 0; k0 < DIM; k0 += 32) {
    bf16x8 af = ldb(ap + k0);
#pragma unroll
    for (int jt = 0; jt < 4; ++jt)
      acc[jt] = MFMA16(af, ldb(bp + (size_t)jt * 16 * DIM + k0), acc[jt]);
  }
#pragma unroll
  for (int jt = 0; jt < 4; ++jt)
#pragma unroll
    for (int i = 0; i < 4; ++i) {
      size_t row = r0 + lg * 4 + i;
      int col = c0 + jt * 16 + lm;
      out[row * DIM + col] = acc[jt][i] + o_b[col] + x[row * DIM + col];
    }
}

extern "C" void kernel_launch(void* const* d_in, const int* in_sizes, int n_in,
                              void* d_out, int out_size, void* d_ws, size_t ws_size,
                              hipStream_t stream) {
  const float* x    = (const float*)d_in[0];
  // d_in[1] = invalid_attn_mask: structurally causal tril; applied as predicate.
  const float* uvqk = (const float*)d_in[2];
  const float* o_w  = (const float*)d_in[3];
  const float* o_b  = (const float*)d_in[4];
  float* out = (float*)d_out;

  u16* uvqk_t = (u16*)d_ws;                         // [2048][512] bf16
  u16* ow_bf  = uvqk_t + (size_t)EDIM * DIM;        // [512][512]  bf16
  u16* xn     = ow_bf + (size_t)DIM * DIM;          // [8192][512] bf16
  u16* proj   = xn + (size_t)BNROWS * DIM;          // [8192][2048] bf16
  float* attn = (float*)(proj + (size_t)BNROWS * EDIM); // [8192][512] f32
  u16* o_in   = (u16*)(attn + (size_t)BNROWS * DIM);    // [8192][512] bf16

  k_cast_uvqk<<<dim3(64, 16), 256, 0, stream>>>(uvqk, uvqk_t);
  k_cast_ow<<<dim3(1024), 256, 0, stream>>>(o_w, ow_bf);
  k_ln1<<<dim3(2048), 256, 0, stream>>>(x, xn);
  k_gemm1<<<dim3(32, 128), 256, 0, stream>>>(xn, uvqk_t, proj);
  k_attn<<<dim3(32, 32), 256, 0, stream>>>(proj, attn);
  k_ln2<<<dim3(2048), 256, 0, stream>>>(attn, proj, o_in);
  k_gemm2<<<dim3(8, 128), 256, 0, stream>>>(o_in, ow_bf, o_b, x, out);
}

// Round 3
// 325.785 us; speedup vs baseline: 1.0869x; 1.0869x over previous
//
#include <hip/hip_runtime.h>
#include <cstdint>

#define NTOK 2048
#define DIM 512
#define EDIM 2048
#define BATCH 4
#define HEADS 8
#define BNROWS 8192   /* B*N */
#define INV_N (1.0f/2048.0f)

typedef unsigned short u16;
typedef __bf16 bf16x8 __attribute__((ext_vector_type(8)));
typedef u16   u16x8  __attribute__((ext_vector_type(8)));
typedef float f32x4  __attribute__((ext_vector_type(4)));

__device__ __forceinline__ u16 f2bf(float f) {
  union { float f; uint32_t u; } v; v.f = f;
  uint32_t r = v.u + 0x7FFFu + ((v.u >> 16) & 1u);   // RNE
  return (u16)(r >> 16);
}
__device__ __forceinline__ float bf2f(u16 b) {
  union { uint32_t u; float f; } v; v.u = ((uint32_t)b) << 16;
  return v.f;
}
__device__ __forceinline__ bf16x8 ldb(const u16* p) {
  u16x8 r = *(const u16x8*)p;
  return __builtin_bit_cast(bf16x8, r);
}
#define MFMA16(a,b,c) __builtin_amdgcn_mfma_f32_16x16x32_bf16((a),(b),(c),0,0,0)

__device__ __forceinline__ float silu_f(float s) {
  return s / (1.0f + __expf(-s));
}

// async global->LDS, 16B per lane; lds base must be wave-uniform
__device__ __forceinline__ void gload16(const u16* g, u16* lds) {
  __builtin_amdgcn_global_load_lds(
      (const __attribute__((address_space(1))) void*)g,
      (__attribute__((address_space(3))) void*)lds, 16, 0, 0);
}

// ---------------- cast / transpose weights ----------------
// uvqk: f32 [512][2048] -> bf16 [2048][512] (transposed)
__global__ __launch_bounds__(256) void k_cast_uvqk(const float* __restrict__ in,
                                                   u16* __restrict__ out) {
  __shared__ float tile[32][33];
  int tx = threadIdx.x & 31, ty = threadIdx.x >> 5;
  int j0 = blockIdx.x * 32;
  int k0 = blockIdx.y * 32;
#pragma unroll
  for (int r = ty; r < 32; r += 8)
    tile[r][tx] = in[(size_t)(k0 + r) * EDIM + j0 + tx];
  __syncthreads();
#pragma unroll
  for (int r = ty; r < 32; r += 8)
    out[(size_t)(j0 + r) * DIM + k0 + tx] = f2bf(tile[tx][r]);
}

// o_w: f32 [512][512] -> bf16
__global__ __launch_bounds__(256) void k_cast_ow(const float* __restrict__ in,
                                                 u16* __restrict__ out) {
  int i = blockIdx.x * 256 + threadIdx.x;
  out[i] = f2bf(in[i]);
}

// ---------------- LayerNorm(x) -> bf16 ----------------
__global__ __launch_bounds__(256) void k_ln1(const float* __restrict__ x,
                                             u16* __restrict__ xn) {
  int lane = threadIdx.x & 63, wid = threadIdx.x >> 6;
  size_t row = (size_t)blockIdx.x * 4 + wid;
  const float* xr = x + row * DIM;
  float4 a = ((const float4*)xr)[lane * 2];
  float4 b = ((const float4*)xr)[lane * 2 + 1];
  float s = a.x + a.y + a.z + a.w + b.x + b.y + b.z + b.w;
#pragma unroll
  for (int o = 32; o; o >>= 1) s += __shfl_xor(s, o);
  float mu = s * (1.0f / DIM);
  float d[8] = {a.x - mu, a.y - mu, a.z - mu, a.w - mu,
                b.x - mu, b.y - mu, b.z - mu, b.w - mu};
  float v = 0.f;
#pragma unroll
  for (int j = 0; j < 8; ++j) v += d[j] * d[j];
#pragma unroll
  for (int o = 32; o; o >>= 1) v += __shfl_xor(v, o);
  float rs = rsqrtf(v * (1.0f / DIM) + 1e-6f);
  u16x8 o8;
#pragma unroll
  for (int j = 0; j < 8; ++j) o8[j] = f2bf(d[j] * rs);
  *(u16x8*)(xn + row * DIM + lane * 8) = o8;
}

// ---------------- GEMM1 (m97 structure): proj = silu(xn @ uvqk) ----------------
// A: bf16 [8192][512]; Bt: bf16 [2048][512]; P: bf16 [8192][2048]
// 128x128 tile, BK=64, 4 waves (2x2), 64x64 per wave, global_load_lds staging.
__global__ __launch_bounds__(256) void k_gemm1(const u16* __restrict__ A,
                                               const u16* __restrict__ Bt,
                                               u16* __restrict__ P) {
  __shared__ u16 As[128 * 64];
  __shared__ u16 Bs[128 * 64];
  int tid = threadIdx.x, lane = tid & 63, wid = tid >> 6;
  int lm = lane & 15, lg = lane >> 4;
  int wr = wid >> 1, wc = wid & 1;
  int r0 = blockIdx.y * 128;
  int c0 = blockIdx.x * 128;

  int srow = wid * 8 + (lane >> 3);     // staging row this lane covers (per it*32)
  int scol = (lane & 7) * 8;            // staging col (u16)

  f32x4 acc[4][4];
  f32x4 z = {0.f, 0.f, 0.f, 0.f};
#pragma unroll
  for (int mt = 0; mt < 4; ++mt)
#pragma unroll
    for (int nt = 0; nt < 4; ++nt) acc[mt][nt] = z;

  for (int ks = 0; ks < DIM / 64; ++ks) {
    // ---- stage A and B tiles (16KB each) ----
#pragma unroll
    for (int it = 0; it < 4; ++it) {
      gload16(A + (size_t)(r0 + it * 32 + srow) * DIM + ks * 64 + scol,
              As + it * 2048 + wid * 512);
      gload16(Bt + (size_t)(c0 + it * 32 + srow) * DIM + ks * 64 + scol,
              Bs + it * 2048 + wid * 512);
    }
    __syncthreads();   // drains vmcnt -> tiles ready

#pragma unroll
    for (int kk = 0; kk < 2; ++kk) {
      bf16x8 am[4], bn[4];
#pragma unroll
      for (int mt = 0; mt < 4; ++mt)
        am[mt] = ldb(&As[(wr * 64 + mt * 16 + lm) * 64 + kk * 32 + lg * 8]);
#pragma unroll
      for (int nt = 0; nt < 4; ++nt)
        bn[nt] = ldb(&Bs[(wc * 64 + nt * 16 + lm) * 64 + kk * 32 + lg * 8]);
#pragma unroll
      for (int mt = 0; mt < 4; ++mt)
#pragma unroll
        for (int nt = 0; nt < 4; ++nt)
          acc[mt][nt] = MFMA16(am[mt], bn[nt], acc[mt][nt]);
    }
    __syncthreads();   // reads done before next overwrite
  }

#pragma unroll
  for (int mt = 0; mt < 4; ++mt)
#pragma unroll
    for (int nt = 0; nt < 4; ++nt)
#pragma unroll
      for (int i = 0; i < 4; ++i) {
        size_t row = r0 + wr * 64 + mt * 16 + lg * 4 + i;
        int col = c0 + wc * 64 + nt * 16 + lm;
        P[row * EDIM + col] = f2bf(silu_f(acc[mt][nt][i]));
      }
}

// ---------------- V^T transpose: vt[bh][e 64][n 2048] ----------------
__global__ __launch_bounds__(256) void k_vt(const u16* __restrict__ proj,
                                            u16* __restrict__ vt) {
  __shared__ u16 t[64][72];
  int tid = threadIdx.x;
  int bh = blockIdx.y, b = bh >> 3, h = bh & 7;
  int n0 = blockIdx.x * 64;
#pragma unroll
  for (int it = 0; it < 2; ++it) {
    int row = it * 32 + (tid >> 3), col = (tid & 7) * 8;
    *(u16x8*)&t[row][col] =
        *(const u16x8*)(proj + (size_t)(b * NTOK + n0 + row) * EDIM + 512 + h * 64 + col);
  }
  __syncthreads();
#pragma unroll
  for (int it = 0; it < 2; ++it) {
    int erow = it * 32 + (tid >> 3), ncol = (tid & 7) * 8;
    u16x8 o;
#pragma unroll
    for (int j = 0; j < 8; ++j) o[j] = t[ncol + j][erow];
    *(u16x8*)(vt + ((size_t)bh * 64 + erow) * NTOK + n0 + ncol) = o;
  }
}

// ---------------- HSTU attention (no K/V staging, no barriers) ----------------
// proj bf16 [8192][2048]: u[0:512] v[512:1024] q[1024:1536] k[1536:2048]
// vt bf16 [32][64][2048]; attn f32 [8192][512]
__global__ __launch_bounds__(256) void k_attn(const u16* __restrict__ proj,
                                              const u16* __restrict__ vt,
                                              float* __restrict__ attn) {
  __shared__ u16 p_lds[4][16][40];
  int tid = threadIdx.x, lane = tid & 63, wid = tid >> 6;
  int lm = lane & 15, lg = lane >> 4;

  // XCD-chunked remap: each XCD owns 4 heads entirely; descending qt = LPT.
  int bid = blockIdx.y * gridDim.x + blockIdx.x;   // 0..1023
  int xcd = bid & 7, idx = bid >> 3;               // idx 0..127
  int bh = xcd * 4 + (idx >> 5);                   // 0..31
  int qt = 31 - (idx & 31);                        // 0..31, big blocks first
  int b = bh >> 3, h = bh & 7;

  const u16* pb = proj + (size_t)b * NTOK * EDIM;
  const u16* kb = pb + 1536 + h * 64;
  const u16* vb = vt + (size_t)bh * 64 * NTOK;
  int nw = qt * 64 + wid * 16;

  const u16* qrow = pb + (size_t)(nw + lm) * EDIM + 1024 + h * 64 + lg * 8;
  bf16x8 qf0 = ldb(qrow), qf1 = ldb(qrow + 32);

  f32x4 z = {0.f, 0.f, 0.f, 0.f};
  f32x4 acc[4];
#pragma unroll
  for (int i = 0; i < 4; ++i) acc[i] = z;

  for (int m0 = 0; m0 <= nw + 15; m0 += 32) {
    const u16* k0p = kb + (size_t)(m0 + lm) * EDIM + lg * 8;
    const u16* k1p = k0p + (size_t)16 * EDIM;
    bf16x8 ka0 = ldb(k0p), kb0 = ldb(k0p + 32);
    bf16x8 ka1 = ldb(k1p), kb1 = ldb(k1p + 32);
    f32x4 s0 = MFMA16(qf0, ka0, z);
    s0 = MFMA16(qf1, kb0, s0);
    f32x4 s1 = MFMA16(qf0, ka1, z);
    s1 = MFMA16(qf1, kb1, s1);
#pragma unroll
    for (int i = 0; i < 4; ++i) {
      int n = nw + lg * 4 + i;
      float pa = s0[i], pbv = s1[i];
      pa  = (m0 + lm <= n)      ? silu_f(pa) * INV_N : 0.f;
      pbv = (m0 + 16 + lm <= n) ? silu_f(pbv) * INV_N : 0.f;
      p_lds[wid][lg * 4 + i][lm] = f2bf(pa);
      p_lds[wid][lg * 4 + i][16 + lm] = f2bf(pbv);
    }
    bf16x8 pf = ldb(&p_lds[wid][lm][lg * 8]);   // same-wave dep, lgkmcnt handles
#pragma unroll
    for (int et = 0; et < 4; ++et) {
      bf16x8 vf = ldb(vb + (size_t)(et * 16 + lm) * NTOK + m0 + lg * 8);
      acc[et] = MFMA16(pf, vf, acc[et]);
    }
  }

#pragma unroll
  for (int et = 0; et < 4; ++et)
#pragma unroll
    for (int i = 0; i < 4; ++i)
      attn[((size_t)b * NTOK + nw + lg * 4 + i) * DIM + h * 64 + et * 16 + lm] =
          acc[et][i];
}

// ---------------- LN(attn) * u -> bf16 ----------------
__global__ __launch_bounds__(256) void k_ln2(const float* __restrict__ attn,
                                             const u16* __restrict__ proj,
                                             u16* __restrict__ o_in) {
  int lane = threadIdx.x & 63, wid = threadIdx.x >> 6;
  size_t row = (size_t)blockIdx.x * 4 + wid;
  const float* ar = attn + row * DIM;
  float4 a = ((const float4*)ar)[lane * 2];
  float4 b = ((const float4*)ar)[lane * 2 + 1];
  float s = a.x + a.y + a.z + a.w + b.x + b.y + b.z + b.w;
#pragma unroll
  for (int o = 32; o; o >>= 1) s += __shfl_xor(s, o);
  float mu = s * (1.0f / DIM);
  float d[8] = {a.x - mu, a.y - mu, a.z - mu, a.w - mu,
                b.x - mu, b.y - mu, b.z - mu, b.w - mu};
  float v = 0.f;
#pragma unroll
  for (int j = 0; j < 8; ++j) v += d[j] * d[j];
#pragma unroll
  for (int o = 32; o; o >>= 1) v += __shfl_xor(v, o);
  float rs = rsqrtf(v * (1.0f / DIM) + 1e-6f);
  u16x8 u8 = *(const u16x8*)(proj + row * EDIM + lane * 8);
  u16x8 o8;
#pragma unroll
  for (int j = 0; j < 8; ++j) o8[j] = f2bf(bf2f(u8[j]) * (d[j] * rs));
  *(u16x8*)(o_in + row * DIM + lane * 8) = o8;
}

// ---------------- GEMM2: out = o_in @ o_w^T + o_b + x ----------------
__global__ __launch_bounds__(256) void k_gemm2(const u16* __restrict__ A,
                                               const u16* __restrict__ Bw,
                                               const float* __restrict__ o_b,
                                               const float* __restrict__ x,
                                               float* __restrict__ out) {
  int lane = threadIdx.x & 63, wid = threadIdx.x >> 6;
  int lm = lane & 15, lg = lane >> 4;
  int r0 = blockIdx.y * 64 + wid * 16;
  int c0 = blockIdx.x * 64;
  const u16* ap = A + (size_t)(r0 + lm) * DIM + lg * 8;
  const u16* bp = Bw + (size_t)(c0 + lm) * DIM + lg * 8;
  f32x4 acc[4];
  f32x4 z = {0.f, 0.f, 0.f, 0.f};
#pragma unroll
  for (int jt = 0; jt < 4; ++jt) acc[jt] = z;
#pragma unroll 4
  for (int k0 = 0; k0 < DIM; k0 += 32) {
    bf16x8 af = ldb(ap + k0);
#pragma unroll
    for (int jt = 0; jt < 4; ++jt)
      acc[jt] = MFMA16(af, ldb(bp + (size_t)jt * 16 * DIM + k0), acc[jt]);
  }
#pragma unroll
  for (int jt = 0; jt < 4; ++jt)
#pragma unroll
    for (int i = 0; i < 4; ++i) {
      size_t row = r0 + lg * 4 + i;
      int col = c0 + jt * 16 + lm;
      out[row * DIM + col] = acc[jt][i] + o_b[col] + x[row * DIM + col];
    }
}

extern "C" void kernel_launch(void* const* d_in, const int* in_sizes, int n_in,
                              void* d_out, int out_size, void* d_ws, size_t ws_size,
                              hipStream_t stream) {
  const float* x    = (const float*)d_in[0];
  // d_in[1] = invalid_attn_mask: structurally causal tril; applied as predicate.
  const float* uvqk = (const float*)d_in[2];
  const float* o_w  = (const float*)d_in[3];
  const float* o_b  = (const float*)d_in[4];
  float* out = (float*)d_out;

  u16* uvqk_t = (u16*)d_ws;                         // [2048][512] bf16   2MB
  u16* ow_bf  = uvqk_t + (size_t)EDIM * DIM;        // [512][512]  bf16   0.5MB
  u16* xn     = ow_bf + (size_t)DIM * DIM;          // [8192][512] bf16   8MB
  u16* proj   = xn + (size_t)BNROWS * DIM;          // [8192][2048] bf16  32MB
  float* attn = (float*)(proj + (size_t)BNROWS * EDIM); // [8192][512] f32 16MB
  u16* o_in   = (u16*)(attn + (size_t)BNROWS * DIM);    // [8192][512] bf16 8MB
  u16* vt     = o_in + (size_t)BNROWS * DIM;            // [32][64][2048] bf16 8MB

  k_cast_uvqk<<<dim3(64, 16), 256, 0, stream>>>(uvqk, uvqk_t);
  k_cast_ow<<<dim3(1024), 256, 0, stream>>>(o_w, ow_bf);
  k_ln1<<<dim3(2048), 256, 0, stream>>>(x, xn);
  k_gemm1<<<dim3(16, 64), 256, 0, stream>>>(xn, uvqk_t, proj);
  k_vt<<<dim3(32, 32), 256, 0, stream>>>(proj, vt);
  k_attn<<<dim3(32, 32), 256, 0, stream>>>(proj, vt, attn);
  k_ln2<<<dim3(2048), 256, 0, stream>>>(attn, proj, o_in);
  k_gemm2<<<dim3(8, 128), 256, 0, stream>>>(o_in, ow_bf, o_b, x, out);
}

// Round 4
// 208.533 us; speedup vs baseline: 1.6981x; 1.5623x over previous
//
#include <hip/hip_runtime.h>
#include <cstdint>

#define NTOK 2048
#define DIM 512
#define EDIM 2048
#define BATCH 4
#define HEADS 8
#define BNROWS 8192   /* B*N */
#define INV_N (1.0f/2048.0f)

typedef unsigned short u16;
typedef __bf16 bf16x8 __attribute__((ext_vector_type(8)));
typedef u16   u16x8  __attribute__((ext_vector_type(8)));
typedef float f32x4  __attribute__((ext_vector_type(4)));

__device__ __forceinline__ u16 f2bf(float f) {
  union { float f; uint32_t u; } v; v.f = f;
  uint32_t r = v.u + 0x7FFFu + ((v.u >> 16) & 1u);   // RNE
  return (u16)(r >> 16);
}
__device__ __forceinline__ float bf2f(u16 b) {
  union { uint32_t u; float f; } v; v.u = ((uint32_t)b) << 16;
  return v.f;
}
__device__ __forceinline__ bf16x8 ldb(const u16* p) {
  u16x8 r = *(const u16x8*)p;
  return __builtin_bit_cast(bf16x8, r);
}
#define MFMA16(a,b,c) __builtin_amdgcn_mfma_f32_16x16x32_bf16((a),(b),(c),0,0,0)

__device__ __forceinline__ float silu_f(float s) {
  return s / (1.0f + __expf(-s));
}

// async global->LDS, 16B per lane; lds base must be wave-uniform
__device__ __forceinline__ void gload16(const u16* g, u16* lds) {
  __builtin_amdgcn_global_load_lds(
      (const __attribute__((address_space(1))) void*)g,
      (__attribute__((address_space(3))) void*)lds, 16, 0, 0);
}

// ---------------- cast / transpose weights ----------------
__global__ __launch_bounds__(256) void k_cast_uvqk(const float* __restrict__ in,
                                                   u16* __restrict__ out) {
  __shared__ float tile[32][33];
  int tx = threadIdx.x & 31, ty = threadIdx.x >> 5;
  int j0 = blockIdx.x * 32;
  int k0 = blockIdx.y * 32;
#pragma unroll
  for (int r = ty; r < 32; r += 8)
    tile[r][tx] = in[(size_t)(k0 + r) * EDIM + j0 + tx];
  __syncthreads();
#pragma unroll
  for (int r = ty; r < 32; r += 8)
    out[(size_t)(j0 + r) * DIM + k0 + tx] = f2bf(tile[tx][r]);
}

__global__ __launch_bounds__(256) void k_cast_ow(const float* __restrict__ in,
                                                 u16* __restrict__ out) {
  int i = blockIdx.x * 256 + threadIdx.x;
  out[i] = f2bf(in[i]);
}

// ---------------- LayerNorm(x) -> bf16 ----------------
__global__ __launch_bounds__(256) void k_ln1(const float* __restrict__ x,
                                             u16* __restrict__ xn) {
  int lane = threadIdx.x & 63, wid = threadIdx.x >> 6;
  size_t row = (size_t)blockIdx.x * 4 + wid;
  const float* xr = x + row * DIM;
  float4 a = ((const float4*)xr)[lane * 2];
  float4 b = ((const float4*)xr)[lane * 2 + 1];
  float s = a.x + a.y + a.z + a.w + b.x + b.y + b.z + b.w;
#pragma unroll
  for (int o = 32; o; o >>= 1) s += __shfl_xor(s, o);
  float mu = s * (1.0f / DIM);
  float d[8] = {a.x - mu, a.y - mu, a.z - mu, a.w - mu,
                b.x - mu, b.y - mu, b.z - mu, b.w - mu};
  float v = 0.f;
#pragma unroll
  for (int j = 0; j < 8; ++j) v += d[j] * d[j];
#pragma unroll
  for (int o = 32; o; o >>= 1) v += __shfl_xor(v, o);
  float rs = rsqrtf(v * (1.0f / DIM) + 1e-6f);
  u16x8 o8;
#pragma unroll
  for (int j = 0; j < 8; ++j) o8[j] = f2bf(d[j] * rs);
  *(u16x8*)(xn + row * DIM + lane * 8) = o8;
}

// ---------------- GEMM1 (m97 structure): proj = silu(xn @ uvqk) ----------------
__global__ __launch_bounds__(256) void k_gemm1(const u16* __restrict__ A,
                                               const u16* __restrict__ Bt,
                                               u16* __restrict__ P) {
  __shared__ u16 As[128 * 64];
  __shared__ u16 Bs[128 * 64];
  int tid = threadIdx.x, lane = tid & 63, wid = tid >> 6;
  int lm = lane & 15, lg = lane >> 4;
  int wr = wid >> 1, wc = wid & 1;
  int r0 = blockIdx.y * 128;
  int c0 = blockIdx.x * 128;

  int srow = wid * 8 + (lane >> 3);
  int scol = (lane & 7) * 8;

  f32x4 acc[4][4];
  f32x4 z = {0.f, 0.f, 0.f, 0.f};
#pragma unroll
  for (int mt = 0; mt < 4; ++mt)
#pragma unroll
    for (int nt = 0; nt < 4; ++nt) acc[mt][nt] = z;

  for (int ks = 0; ks < DIM / 64; ++ks) {
#pragma unroll
    for (int it = 0; it < 4; ++it) {
      gload16(A + (size_t)(r0 + it * 32 + srow) * DIM + ks * 64 + scol,
              As + it * 2048 + wid * 512);
      gload16(Bt + (size_t)(c0 + it * 32 + srow) * DIM + ks * 64 + scol,
              Bs + it * 2048 + wid * 512);
    }
    __syncthreads();

#pragma unroll
    for (int kk = 0; kk < 2; ++kk) {
      bf16x8 am[4], bn[4];
#pragma unroll
      for (int mt = 0; mt < 4; ++mt)
        am[mt] = ldb(&As[(wr * 64 + mt * 16 + lm) * 64 + kk * 32 + lg * 8]);
#pragma unroll
      for (int nt = 0; nt < 4; ++nt)
        bn[nt] = ldb(&Bs[(wc * 64 + nt * 16 + lm) * 64 + kk * 32 + lg * 8]);
#pragma unroll
      for (int mt = 0; mt < 4; ++mt)
#pragma unroll
        for (int nt = 0; nt < 4; ++nt)
          acc[mt][nt] = MFMA16(am[mt], bn[nt], acc[mt][nt]);
    }
    __syncthreads();
  }

#pragma unroll
  for (int mt = 0; mt < 4; ++mt)
#pragma unroll
    for (int nt = 0; nt < 4; ++nt)
#pragma unroll
      for (int i = 0; i < 4; ++i) {
        size_t row = r0 + wr * 64 + mt * 16 + lg * 4 + i;
        int col = c0 + wc * 64 + nt * 16 + lm;
        P[row * EDIM + col] = f2bf(silu_f(acc[mt][nt][i]));
      }
}

// ---------------- V^T transpose: vt[bh][e 64][n 2048] ----------------
__global__ __launch_bounds__(256) void k_vt(const u16* __restrict__ proj,
                                            u16* __restrict__ vt) {
  __shared__ u16 t[64][72];
  int tid = threadIdx.x;
  int bh = blockIdx.y, b = bh >> 3, h = bh & 7;
  int n0 = blockIdx.x * 64;
#pragma unroll
  for (int it = 0; it < 2; ++it) {
    int row = it * 32 + (tid >> 3), col = (tid & 7) * 8;
    *(u16x8*)&t[row][col] =
        *(const u16x8*)(proj + (size_t)(b * NTOK + n0 + row) * EDIM + 512 + h * 64 + col);
  }
  __syncthreads();
#pragma unroll
  for (int it = 0; it < 2; ++it) {
    int erow = it * 32 + (tid >> 3), ncol = (tid & 7) * 8;
    u16x8 o;
#pragma unroll
    for (int j = 0; j < 8; ++j) o[j] = t[ncol + j][erow];
    *(u16x8*)(vt + ((size_t)bh * 64 + erow) * NTOK + n0 + ncol) = o;
  }
}

// ---------------- HSTU attention v3 ----------------
// Staged K/V^T tiles (XOR-swizzled, gload_lds), double-buffered 2-phase,
// 4 waves x 32 q-rows = 128 q-rows/block, KVBLK=64.
// proj: u[0:512] v[512:1024] q[1024:1536] k[1536:2048]; vt[bh][e 64][n 2048]
__global__ __launch_bounds__(256) void k_attn(const u16* __restrict__ proj,
                                              const u16* __restrict__ vt,
                                              float* __restrict__ attn) {
  __shared__ u16 kv0[8192];                 // K[64][64] | V^T[64][64]
  __shared__ u16 kv1[8192];
  __shared__ u16 p_lds[4][2][16][72];
  int tid = threadIdx.x, lane = tid & 63, w = tid >> 6;
  int lm = lane & 15, lg = lane >> 4;

  // XCD-chunked remap (4 heads per XCD -> 2MB K+V^T in its L2), LPT order.
  int bid = blockIdx.x;                     // 0..511
  int xcd = bid & 7, idx = bid >> 3;        // idx 0..63
  int bh = (xcd << 2) + (idx >> 4);         // 0..31
  int qt = 15 - (idx & 15);                 // big q-tiles first
  int b = bh >> 3, h = bh & 7;
  int n0 = qt * 128;

  const u16* pb = proj + (size_t)b * NTOK * EDIM;
  const u16* kb = pb + 1536 + h * 64;
  const u16* vb = vt + (size_t)bh * 64 * NTOK;

  // Q fragments (2 subtiles x 2 k-halves), held in registers
  bf16x8 qf[2][2];
#pragma unroll
  for (int qs = 0; qs < 2; ++qs) {
    const u16* qrow = pb + (size_t)(n0 + w * 32 + qs * 16 + lm) * EDIM + 1024 + h * 64 + lg * 8;
    qf[qs][0] = ldb(qrow);
    qf[qs][1] = ldb(qrow + 32);
  }

  f32x4 z = {0.f, 0.f, 0.f, 0.f};
  f32x4 acc[2][4];
#pragma unroll
  for (int qs = 0; qs < 2; ++qs)
#pragma unroll
    for (int et = 0; et < 4; ++et) acc[qs][et] = z;

  // staging constants: lane l covers LDS row base+(l>>3), phys 16B slot (l&7);
  // source col pre-swizzled so READ with col^((row&7)<<3) is linear data.
  int sr = lane >> 3;
  int sc = ((lane & 7) ^ sr) * 8;           // u16 units
  const u16* ks0 = kb + (size_t)(w * 16 + sr) * EDIM + sc;
  const u16* ks1 = kb + (size_t)(w * 16 + 8 + sr) * EDIM + sc;
  const u16* vs0 = vb + (size_t)(w * 16 + sr) * NTOK + sc;
  const u16* vs1 = vb + (size_t)(w * 16 + 8 + sr) * NTOK + sc;

  int nt = 2 * qt + 2;
  int wave_nmax = n0 + w * 32 + 31;

  // prologue: stage tile 0 -> kv0
  gload16(ks0, kv0 + (w * 16) * 64);
  gload16(ks1, kv0 + (w * 16 + 8) * 64);
  gload16(vs0, kv0 + 4096 + (w * 16) * 64);
  gload16(vs1, kv0 + 4096 + (w * 16 + 8) * 64);
  asm volatile("s_waitcnt vmcnt(0)" ::: "memory");
  __builtin_amdgcn_s_barrier();

  for (int t = 0; t < nt; ++t) {
    const u16* kt = (t & 1) ? kv1 : kv0;
    const u16* vl = kt + 4096;
    if (t + 1 < nt) {                       // prefetch next tile
      u16* kd = ((t + 1) & 1) ? kv1 : kv0;
      size_t ko = (size_t)(t + 1) * 64 * EDIM;
      size_t vo = (size_t)(t + 1) * 64;
      gload16(ks0 + ko, kd + (w * 16) * 64);
      gload16(ks1 + ko, kd + (w * 16 + 8) * 64);
      gload16(vs0 + vo, kd + 4096 + (w * 16) * 64);
      gload16(vs1 + vo, kd + 4096 + (w * 16 + 8) * 64);
    }
    int m0 = t * 64;
    if (m0 <= wave_nmax) {
      // ---- QK^T: S[q][m], K fragments swizzle-read, reused across 2 q-subtiles
      bf16x8 kf[4][2];
#pragma unroll
      for (int mb = 0; mb < 4; ++mb)
#pragma unroll
        for (int kk = 0; kk < 2; ++kk)
          kf[mb][kk] = ldb(&kt[(mb * 16 + lm) * 64 + ((kk * 32 + lg * 8) ^ ((lm & 7) << 3))]);
#pragma unroll
      for (int qs = 0; qs < 2; ++qs) {
        int nq = n0 + w * 32 + qs * 16 + lg * 4;
#pragma unroll
        for (int mb = 0; mb < 4; ++mb) {
          f32x4 s = MFMA16(qf[qs][0], kf[mb][0], z);
          s = MFMA16(qf[qs][1], kf[mb][1], s);
          int m = m0 + mb * 16 + lm;
#pragma unroll
          for (int i = 0; i < 4; ++i) {
            float p = (m <= nq + i) ? silu_f(s[i]) * INV_N : 0.f;
            p_lds[w][qs][lg * 4 + i][mb * 16 + lm] = f2bf(p);
          }
        }
      }
      // ---- PV: V^T fragments swizzle-read, reused across 2 q-subtiles
      bf16x8 vf[2][4], pf[2][2];
#pragma unroll
      for (int kk = 0; kk < 2; ++kk)
#pragma unroll
        for (int et = 0; et < 4; ++et)
          vf[kk][et] = ldb(&vl[(et * 16 + lm) * 64 + ((kk * 32 + lg * 8) ^ ((lm & 7) << 3))]);
#pragma unroll
      for (int qs = 0; qs < 2; ++qs)
#pragma unroll
        for (int kk = 0; kk < 2; ++kk)
          pf[qs][kk] = ldb(&p_lds[w][qs][lm][kk * 32 + lg * 8]);
#pragma unroll
      for (int qs = 0; qs < 2; ++qs)
#pragma unroll
        for (int et = 0; et < 4; ++et) {
          acc[qs][et] = MFMA16(pf[qs][0], vf[0][et], acc[qs][et]);
          acc[qs][et] = MFMA16(pf[qs][1], vf[1][et], acc[qs][et]);
        }
    }
    asm volatile("s_waitcnt vmcnt(0)" ::: "memory");
    __builtin_amdgcn_s_barrier();
  }

#pragma unroll
  for (int qs = 0; qs < 2; ++qs)
#pragma unroll
    for (int et = 0; et < 4; ++et)
#pragma unroll
      for (int i = 0; i < 4; ++i)
        attn[((size_t)b * NTOK + n0 + w * 32 + qs * 16 + lg * 4 + i) * DIM +
             h * 64 + et * 16 + lm] = acc[qs][et][i];
}

// ---------------- LN(attn) * u -> bf16 ----------------
__global__ __launch_bounds__(256) void k_ln2(const float* __restrict__ attn,
                                             const u16* __restrict__ proj,
                                             u16* __restrict__ o_in) {
  int lane = threadIdx.x & 63, wid = threadIdx.x >> 6;
  size_t row = (size_t)blockIdx.x * 4 + wid;
  const float* ar = attn + row * DIM;
  float4 a = ((const float4*)ar)[lane * 2];
  float4 b = ((const float4*)ar)[lane * 2 + 1];
  float s = a.x + a.y + a.z + a.w + b.x + b.y + b.z + b.w;
#pragma unroll
  for (int o = 32; o; o >>= 1) s += __shfl_xor(s, o);
  float mu = s * (1.0f / DIM);
  float d[8] = {a.x - mu, a.y - mu, a.z - mu, a.w - mu,
                b.x - mu, b.y - mu, b.z - mu, b.w - mu};
  float v = 0.f;
#pragma unroll
  for (int j = 0; j < 8; ++j) v += d[j] * d[j];
#pragma unroll
  for (int o = 32; o; o >>= 1) v += __shfl_xor(v, o);
  float rs = rsqrtf(v * (1.0f / DIM) + 1e-6f);
  u16x8 u8 = *(const u16x8*)(proj + row * EDIM + lane * 8);
  u16x8 o8;
#pragma unroll
  for (int j = 0; j < 8; ++j) o8[j] = f2bf(bf2f(u8[j]) * (d[j] * rs));
  *(u16x8*)(o_in + row * DIM + lane * 8) = o8;
}

// ---------------- GEMM2: out = o_in @ o_w^T + o_b + x ----------------
__global__ __launch_bounds__(256) void k_gemm2(const u16* __restrict__ A,
                                               const u16* __restrict__ Bw,
                                               const float* __restrict__ o_b,
                                               const float* __restrict__ x,
                                               float* __restrict__ out) {
  int lane = threadIdx.x & 63, wid = threadIdx.x >> 6;
  int lm = lane & 15, lg = lane >> 4;
  int r0 = blockIdx.y * 64 + wid * 16;
  int c0 = blockIdx.x * 64;
  const u16* ap = A + (size_t)(r0 + lm) * DIM + lg * 8;
  const u16* bp = Bw + (size_t)(c0 + lm) * DIM + lg * 8;
  f32x4 acc[4];
  f32x4 z = {0.f, 0.f, 0.f, 0.f};
#pragma unroll
  for (int jt = 0; jt < 4; ++jt) acc[jt] = z;
#pragma unroll 4
  for (int k0 = 0; k0 < DIM; k0 += 32) {
    bf16x8 af = ldb(ap + k0);
#pragma unroll
    for (int jt = 0; jt < 4; ++jt)
      acc[jt] = MFMA16(af, ldb(bp + (size_t)jt * 16 * DIM + k0), acc[jt]);
  }
#pragma unroll
  for (int jt = 0; jt < 4; ++jt)
#pragma unroll
    for (int i = 0; i < 4; ++i) {
      size_t row = r0 + lg * 4 + i;
      int col = c0 + jt * 16 + lm;
      out[row * DIM + col] = acc[jt][i] + o_b[col] + x[row * DIM + col];
    }
}

extern "C" void kernel_launch(void* const* d_in, const int* in_sizes, int n_in,
                              void* d_out, int out_size, void* d_ws, size_t ws_size,
                              hipStream_t stream) {
  const float* x    = (const float*)d_in[0];
  // d_in[1] = invalid_attn_mask: structurally causal tril; applied as predicate.
  const float* uvqk = (const float*)d_in[2];
  const float* o_w  = (const float*)d_in[3];
  const float* o_b  = (const float*)d_in[4];
  float* out = (float*)d_out;

  u16* uvqk_t = (u16*)d_ws;                         // [2048][512] bf16   2MB
  u16* ow_bf  = uvqk_t + (size_t)EDIM * DIM;        // [512][512]  bf16   0.5MB
  u16* xn     = ow_bf + (size_t)DIM * DIM;          // [8192][512] bf16   8MB
  u16* proj   = xn + (size_t)BNROWS * DIM;          // [8192][2048] bf16  32MB
  float* attn = (float*)(proj + (size_t)BNROWS * EDIM); // [8192][512] f32 16MB
  u16* o_in   = (u16*)(attn + (size_t)BNROWS * DIM);    // [8192][512] bf16 8MB
  u16* vt     = o_in + (size_t)BNROWS * DIM;            // [32][64][2048] bf16 8MB

  k_cast_uvqk<<<dim3(64, 16), 256, 0, stream>>>(uvqk, uvqk_t);
  k_cast_ow<<<dim3(1024), 256, 0, stream>>>(o_w, ow_bf);
  k_ln1<<<dim3(2048), 256, 0, stream>>>(x, xn);
  k_gemm1<<<dim3(16, 64), 256, 0, stream>>>(xn, uvqk_t, proj);
  k_vt<<<dim3(32, 32), 256, 0, stream>>>(proj, vt);
  k_attn<<<dim3(512), 256, 0, stream>>>(proj, vt, attn);
  k_ln2<<<dim3(2048), 256, 0, stream>>>(attn, proj, o_in);
  k_gemm2<<<dim3(8, 128), 256, 0, stream>>>(o_in, ow_bf, o_b, x, out);
}

// Round 5
// 155.802 us; speedup vs baseline: 2.2728x; 1.3385x over previous
//
#include <hip/hip_runtime.h>
#include <cstdint>

#define NTOK 2048
#define DIM 512
#define EDIM 2048
#define BATCH 4
#define HEADS 8
#define BNROWS 8192   /* B*N */
#define INV_N (1.0f/2048.0f)

typedef unsigned short u16;
typedef __bf16 bf16x8 __attribute__((ext_vector_type(8)));
typedef u16   u16x8  __attribute__((ext_vector_type(8)));
typedef u16   u16x4  __attribute__((ext_vector_type(4)));
typedef float f32x4  __attribute__((ext_vector_type(4)));

__device__ __forceinline__ u16 f2bf(float f) {
  union { float f; uint32_t u; } v; v.f = f;
  uint32_t r = v.u + 0x7FFFu + ((v.u >> 16) & 1u);   // RNE
  return (u16)(r >> 16);
}
__device__ __forceinline__ u16 f2bfc(float f) {     // compiler cast (packs to cvt_pk)
  return __builtin_bit_cast(u16, (__bf16)f);
}
__device__ __forceinline__ float bf2f(u16 b) {
  union { uint32_t u; float f; } v; v.u = ((uint32_t)b) << 16;
  return v.f;
}
__device__ __forceinline__ bf16x8 ldb(const u16* p) {
  u16x8 r = *(const u16x8*)p;
  return __builtin_bit_cast(bf16x8, r);
}
#define MFMA16(a,b,c) __builtin_amdgcn_mfma_f32_16x16x32_bf16((a),(b),(c),0,0,0)

__device__ __forceinline__ float silu_f(float s) {
  return s / (1.0f + __expf(-s));
}

// async global->LDS, 16B per lane; lds base must be wave-uniform
__device__ __forceinline__ void gload16(const u16* g, u16* lds) {
  __builtin_amdgcn_global_load_lds(
      (const __attribute__((address_space(1))) void*)g,
      (__attribute__((address_space(3))) void*)lds, 16, 0, 0);
}

// ---------------- cast / transpose weights ----------------
__global__ __launch_bounds__(256) void k_cast_uvqk(const float* __restrict__ in,
                                                   u16* __restrict__ out) {
  __shared__ float tile[32][33];
  int tx = threadIdx.x & 31, ty = threadIdx.x >> 5;
  int j0 = blockIdx.x * 32;
  int k0 = blockIdx.y * 32;
#pragma unroll
  for (int r = ty; r < 32; r += 8)
    tile[r][tx] = in[(size_t)(k0 + r) * EDIM + j0 + tx];
  __syncthreads();
#pragma unroll
  for (int r = ty; r < 32; r += 8)
    out[(size_t)(j0 + r) * DIM + k0 + tx] = f2bf(tile[tx][r]);
}

__global__ __launch_bounds__(256) void k_cast_ow(const float* __restrict__ in,
                                                 u16* __restrict__ out) {
  int i = blockIdx.x * 256 + threadIdx.x;
  out[i] = f2bf(in[i]);
}

// ---------------- LayerNorm(x) -> bf16 ----------------
__global__ __launch_bounds__(256) void k_ln1(const float* __restrict__ x,
                                             u16* __restrict__ xn) {
  int lane = threadIdx.x & 63, wid = threadIdx.x >> 6;
  size_t row = (size_t)blockIdx.x * 4 + wid;
  const float* xr = x + row * DIM;
  float4 a = ((const float4*)xr)[lane * 2];
  float4 b = ((const float4*)xr)[lane * 2 + 1];
  float s = a.x + a.y + a.z + a.w + b.x + b.y + b.z + b.w;
#pragma unroll
  for (int o = 32; o; o >>= 1) s += __shfl_xor(s, o);
  float mu = s * (1.0f / DIM);
  float d[8] = {a.x - mu, a.y - mu, a.z - mu, a.w - mu,
                b.x - mu, b.y - mu, b.z - mu, b.w - mu};
  float v = 0.f;
#pragma unroll
  for (int j = 0; j < 8; ++j) v += d[j] * d[j];
#pragma unroll
  for (int o = 32; o; o >>= 1) v += __shfl_xor(v, o);
  float rs = rsqrtf(v * (1.0f / DIM) + 1e-6f);
  u16x8 o8;
#pragma unroll
  for (int j = 0; j < 8; ++j) o8[j] = f2bf(d[j] * rs);
  *(u16x8*)(xn + row * DIM + lane * 8) = o8;
}

// ---------------- GEMM1 (m97 structure): proj = silu(xn @ uvqk) ----------------
__global__ __launch_bounds__(256) void k_gemm1(const u16* __restrict__ A,
                                               const u16* __restrict__ Bt,
                                               u16* __restrict__ P) {
  __shared__ u16 As[128 * 64];
  __shared__ u16 Bs[128 * 64];
  int tid = threadIdx.x, lane = tid & 63, wid = tid >> 6;
  int lm = lane & 15, lg = lane >> 4;
  int wr = wid >> 1, wc = wid & 1;
  int r0 = blockIdx.y * 128;
  int c0 = blockIdx.x * 128;

  int srow = wid * 8 + (lane >> 3);
  int scol = (lane & 7) * 8;

  f32x4 acc[4][4];
  f32x4 z = {0.f, 0.f, 0.f, 0.f};
#pragma unroll
  for (int mt = 0; mt < 4; ++mt)
#pragma unroll
    for (int nt = 0; nt < 4; ++nt) acc[mt][nt] = z;

  for (int ks = 0; ks < DIM / 64; ++ks) {
#pragma unroll
    for (int it = 0; it < 4; ++it) {
      gload16(A + (size_t)(r0 + it * 32 + srow) * DIM + ks * 64 + scol,
              As + it * 2048 + wid * 512);
      gload16(Bt + (size_t)(c0 + it * 32 + srow) * DIM + ks * 64 + scol,
              Bs + it * 2048 + wid * 512);
    }
    __syncthreads();

#pragma unroll
    for (int kk = 0; kk < 2; ++kk) {
      bf16x8 am[4], bn[4];
#pragma unroll
      for (int mt = 0; mt < 4; ++mt)
        am[mt] = ldb(&As[(wr * 64 + mt * 16 + lm) * 64 + kk * 32 + lg * 8]);
#pragma unroll
      for (int nt = 0; nt < 4; ++nt)
        bn[nt] = ldb(&Bs[(wc * 64 + nt * 16 + lm) * 64 + kk * 32 + lg * 8]);
#pragma unroll
      for (int mt = 0; mt < 4; ++mt)
#pragma unroll
        for (int nt = 0; nt < 4; ++nt)
          acc[mt][nt] = MFMA16(am[mt], bn[nt], acc[mt][nt]);
    }
    __syncthreads();
  }

#pragma unroll
  for (int mt = 0; mt < 4; ++mt)
#pragma unroll
    for (int nt = 0; nt < 4; ++nt)
#pragma unroll
      for (int i = 0; i < 4; ++i) {
        size_t row = r0 + wr * 64 + mt * 16 + lg * 4 + i;
        int col = c0 + wc * 64 + nt * 16 + lm;
        P[row * EDIM + col] = f2bf(silu_f(acc[mt][nt][i]));
      }
}

// ---------------- V^T transpose: vt[bh][e 64][n 2048] ----------------
__global__ __launch_bounds__(256) void k_vt(const u16* __restrict__ proj,
                                            u16* __restrict__ vt) {
  __shared__ u16 t[64][72];
  int tid = threadIdx.x;
  int bh = blockIdx.y, b = bh >> 3, h = bh & 7;
  int n0 = blockIdx.x * 64;
#pragma unroll
  for (int it = 0; it < 2; ++it) {
    int row = it * 32 + (tid >> 3), col = (tid & 7) * 8;
    *(u16x8*)&t[row][col] =
        *(const u16x8*)(proj + (size_t)(b * NTOK + n0 + row) * EDIM + 512 + h * 64 + col);
  }
  __syncthreads();
#pragma unroll
  for (int it = 0; it < 2; ++it) {
    int erow = it * 32 + (tid >> 3), ncol = (tid & 7) * 8;
    u16x8 o;
#pragma unroll
    for (int j = 0; j < 8; ++j) o[j] = t[ncol + j][erow];
    *(u16x8*)(vt + ((size_t)bh * 64 + erow) * NTOK + n0 + ncol) = o;
  }
}

// ---------------- HSTU attention v4 ----------------
// Complementary-paired q-tiles (perfect balance: every block = 33 tile-steps),
// swapped QK^T (S^T in acc -> b64 P-stores), staged K/V^T (swizzled),
// double-buffered. 4 waves x 16 q-rows per phase.
__global__ __launch_bounds__(256) void k_attn(const u16* __restrict__ proj,
                                              const u16* __restrict__ vt,
                                              float* __restrict__ attn) {
  __shared__ u16 kv0[8192];                 // K[64][64] | V^T[64][64]
  __shared__ u16 kv1[8192];
  __shared__ u16 p_lds[4][16][72];          // per-wave P[q 16][m 64] (+pad)
  int tid = threadIdx.x, lane = tid & 63, w = tid >> 6;
  int lm = lane & 15, lg = lane >> 4;

  // XCD-chunked remap: 4 heads per XCD (2MB K+V^T in its L2).
  int bid = blockIdx.x;                     // 0..511
  int xcd = bid & 7, idx = bid >> 3;        // idx 0..63
  int bh = (xcd << 2) + (idx >> 4);         // 0..31
  int pairp = idx & 15;                     // pair index 0..15
  int b = bh >> 3, h = bh & 7;

  const u16* pb = proj + (size_t)b * NTOK * EDIM;
  const u16* kb = pb + 1536 + h * 64;
  const u16* vb = vt + (size_t)bh * 64 * NTOK;

  f32x4 z = {0.f, 0.f, 0.f, 0.f};

  // staging: lane l covers LDS row base+(l>>3), phys 16B slot (l&7);
  // source col pre-swizzled so read with col^((row&7)<<3) is linear data.
  int sr = lane >> 3;
  int sc = ((lane & 7) ^ sr) * 8;           // u16 units
  const u16* ks0 = kb + (size_t)(w * 16 + sr) * EDIM + sc;
  const u16* ks1 = kb + (size_t)(w * 16 + 8 + sr) * EDIM + sc;
  const u16* vs0 = vb + (size_t)(w * 16 + sr) * NTOK + sc;
  const u16* vs1 = vb + (size_t)(w * 16 + 8 + sr) * NTOK + sc;

#pragma unroll
  for (int ph = 0; ph < 2; ++ph) {
    int qtile = ph ? pairp : (31 - pairp);  // phases: (31-p)+1 + p+1 = 33 steps
    int n0 = qtile * 64;
    int nrow = n0 + w * 16;                 // wave's first q row
    int nlm = nrow + lm;                    // this lane's q (column of S^T)

    const u16* qrow = pb + (size_t)nlm * EDIM + 1024 + h * 64 + lg * 8;
    bf16x8 qf0 = ldb(qrow), qf1 = ldb(qrow + 32);

    f32x4 acc[4];
#pragma unroll
    for (int et = 0; et < 4; ++et) acc[et] = z;

    // prologue: stage tile 0 -> kv0
    gload16(ks0, kv0 + (w * 16) * 64);
    gload16(ks1, kv0 + (w * 16 + 8) * 64);
    gload16(vs0, kv0 + 4096 + (w * 16) * 64);
    gload16(vs1, kv0 + 4096 + (w * 16 + 8) * 64);
    asm volatile("s_waitcnt vmcnt(0)" ::: "memory");
    __builtin_amdgcn_s_barrier();

    int ntl = qtile + 1;
    for (int t = 0; t < ntl; ++t) {
      const u16* kt = (t & 1) ? kv1 : kv0;
      const u16* vl = kt + 4096;
      if (t + 1 < ntl) {                    // prefetch next tile
        u16* kd = ((t + 1) & 1) ? kv1 : kv0;
        size_t ko = (size_t)(t + 1) * 64 * EDIM;
        size_t vo = (size_t)(t + 1) * 64;
        gload16(ks0 + ko, kd + (w * 16) * 64);
        gload16(ks1 + ko, kd + (w * 16 + 8) * 64);
        gload16(vs0 + vo, kd + 4096 + (w * 16) * 64);
        gload16(vs1 + vo, kd + 4096 + (w * 16 + 8) * 64);
      }
      // ---- QK^T swapped: S^T[m][q]; K as A-frag (same lane map as B-frag)
      bf16x8 kf[4][2];
#pragma unroll
      for (int mb = 0; mb < 4; ++mb)
#pragma unroll
        for (int kk = 0; kk < 2; ++kk)
          kf[mb][kk] = ldb(&kt[(mb * 16 + lm) * 64 +
                               ((kk * 32 + lg * 8) ^ ((lm & 7) << 3))]);
      if (t == qtile) {                     // diagonal tile: masked (wave-uniform)
#pragma unroll
        for (int mb = 0; mb < 4; ++mb) {
          f32x4 s = MFMA16(kf[mb][0], qf0, z);
          s = MFMA16(kf[mb][1], qf1, s);
          int m = t * 64 + mb * 16 + lg * 4;
          u16x4 pk;
#pragma unroll
          for (int i = 0; i < 4; ++i)
            pk[i] = (m + i <= nlm) ? f2bfc(silu_f(s[i])) : (u16)0;
          *(u16x4*)&p_lds[w][lm][mb * 16 + lg * 4] = pk;
        }
      } else {                              // full tile: no mask
#pragma unroll
        for (int mb = 0; mb < 4; ++mb) {
          f32x4 s = MFMA16(kf[mb][0], qf0, z);
          s = MFMA16(kf[mb][1], qf1, s);
          u16x4 pk;
#pragma unroll
          for (int i = 0; i < 4; ++i) pk[i] = f2bfc(silu_f(s[i]));
          *(u16x4*)&p_lds[w][lm][mb * 16 + lg * 4] = pk;
        }
      }
      // ---- PV: A = P (rows q, k=m), B = V^T frag
      bf16x8 vf[2][4];
#pragma unroll
      for (int kk = 0; kk < 2; ++kk)
#pragma unroll
        for (int et = 0; et < 4; ++et)
          vf[kk][et] = ldb(&vl[(et * 16 + lm) * 64 +
                               ((kk * 32 + lg * 8) ^ ((lm & 7) << 3))]);
      bf16x8 pf0 = ldb(&p_lds[w][lm][lg * 8]);
      bf16x8 pf1 = ldb(&p_lds[w][lm][32 + lg * 8]);
#pragma unroll
      for (int et = 0; et < 4; ++et) {
        acc[et] = MFMA16(pf0, vf[0][et], acc[et]);
        acc[et] = MFMA16(pf1, vf[1][et], acc[et]);
      }
      asm volatile("s_waitcnt vmcnt(0)" ::: "memory");
      __builtin_amdgcn_s_barrier();
    }

#pragma unroll
    for (int et = 0; et < 4; ++et)
#pragma unroll
      for (int i = 0; i < 4; ++i)
        attn[((size_t)b * NTOK + nrow + lg * 4 + i) * DIM +
             h * 64 + et * 16 + lm] = acc[et][i] * INV_N;
  }
}

// ---------------- LN(attn) * u -> bf16 ----------------
__global__ __launch_bounds__(256) void k_ln2(const float* __restrict__ attn,
                                             const u16* __restrict__ proj,
                                             u16* __restrict__ o_in) {
  int lane = threadIdx.x & 63, wid = threadIdx.x >> 6;
  size_t row = (size_t)blockIdx.x * 4 + wid;
  const float* ar = attn + row * DIM;
  float4 a = ((const float4*)ar)[lane * 2];
  float4 b = ((const float4*)ar)[lane * 2 + 1];
  float s = a.x + a.y + a.z + a.w + b.x + b.y + b.z + b.w;
#pragma unroll
  for (int o = 32; o; o >>= 1) s += __shfl_xor(s, o);
  float mu = s * (1.0f / DIM);
  float d[8] = {a.x - mu, a.y - mu, a.z - mu, a.w - mu,
                b.x - mu, b.y - mu, b.z - mu, b.w - mu};
  float v = 0.f;
#pragma unroll
  for (int j = 0; j < 8; ++j) v += d[j] * d[j];
#pragma unroll
  for (int o = 32; o; o >>= 1) v += __shfl_xor(v, o);
  float rs = rsqrtf(v * (1.0f / DIM) + 1e-6f);
  u16x8 u8 = *(const u16x8*)(proj + row * EDIM + lane * 8);
  u16x8 o8;
#pragma unroll
  for (int j = 0; j < 8; ++j) o8[j] = f2bf(bf2f(u8[j]) * (d[j] * rs));
  *(u16x8*)(o_in + row * DIM + lane * 8) = o8;
}

// ---------------- GEMM2: out = o_in @ o_w^T + o_b + x ----------------
__global__ __launch_bounds__(256) void k_gemm2(const u16* __restrict__ A,
                                               const u16* __restrict__ Bw,
                                               const float* __restrict__ o_b,
                                               const float* __restrict__ x,
                                               float* __restrict__ out) {
  int lane = threadIdx.x & 63, wid = threadIdx.x >> 6;
  int lm = lane & 15, lg = lane >> 4;
  int r0 = blockIdx.y * 64 + wid * 16;
  int c0 = blockIdx.x * 64;
  const u16* ap = A + (size_t)(r0 + lm) * DIM + lg * 8;
  const u16* bp = Bw + (size_t)(c0 + lm) * DIM + lg * 8;
  f32x4 acc[4];
  f32x4 z = {0.f, 0.f, 0.f, 0.f};
#pragma unroll
  for (int jt = 0; jt < 4; ++jt) acc[jt] = z;
#pragma unroll 4
  for (int k0 = 0; k0 < DIM; k0 += 32) {
    bf16x8 af = ldb(ap + k0);
#pragma unroll
    for (int jt = 0; jt < 4; ++jt)
      acc[jt] = MFMA16(af, ldb(bp + (size_t)jt * 16 * DIM + k0), acc[jt]);
  }
#pragma unroll
  for (int jt = 0; jt < 4; ++jt)
#pragma unroll
    for (int i = 0; i < 4; ++i) {
      size_t row = r0 + lg * 4 + i;
      int col = c0 + jt * 16 + lm;
      out[row * DIM + col] = acc[jt][i] + o_b[col] + x[row * DIM + col];
    }
}

extern "C" void kernel_launch(void* const* d_in, const int* in_sizes, int n_in,
                              void* d_out, int out_size, void* d_ws, size_t ws_size,
                              hipStream_t stream) {
  const float* x    = (const float*)d_in[0];
  // d_in[1] = invalid_attn_mask: structurally causal tril; applied as predicate.
  const float* uvqk = (const float*)d_in[2];
  const float* o_w  = (const float*)d_in[3];
  const float* o_b  = (const float*)d_in[4];
  float* out = (float*)d_out;

  u16* uvqk_t = (u16*)d_ws;                         // [2048][512] bf16   2MB
  u16* ow_bf  = uvqk_t + (size_t)EDIM * DIM;        // [512][512]  bf16   0.5MB
  u16* xn     = ow_bf + (size_t)DIM * DIM;          // [8192][512] bf16   8MB
  u16* proj   = xn + (size_t)BNROWS * DIM;          // [8192][2048] bf16  32MB
  float* attn = (float*)(proj + (size_t)BNROWS * EDIM); // [8192][512] f32 16MB
  u16* o_in   = (u16*)(attn + (size_t)BNROWS * DIM);    // [8192][512] bf16 8MB
  u16* vt     = o_in + (size_t)BNROWS * DIM;            // [32][64][2048] bf16 8MB

  k_cast_uvqk<<<dim3(64, 16), 256, 0, stream>>>(uvqk, uvqk_t);
  k_cast_ow<<<dim3(1024), 256, 0, stream>>>(o_w, ow_bf);
  k_ln1<<<dim3(2048), 256, 0, stream>>>(x, xn);
  k_gemm1<<<dim3(16, 64), 256, 0, stream>>>(xn, uvqk_t, proj);
  k_vt<<<dim3(32, 32), 256, 0, stream>>>(proj, vt);
  k_attn<<<dim3(512), 256, 0, stream>>>(proj, vt, attn);
  k_ln2<<<dim3(2048), 256, 0, stream>>>(attn, proj, o_in);
  k_gemm2<<<dim3(8, 128), 256, 0, stream>>>(o_in, ow_bf, o_b, x, out);
}

// Round 7
// 152.744 us; speedup vs baseline: 2.3183x; 1.0200x over previous
//
#include <hip/hip_runtime.h>
#include <cstdint>

#define NTOK 2048
#define DIM 512
#define EDIM 2048
#define BATCH 4
#define HEADS 8
#define BNROWS 8192   /* B*N */
#define INV_N (1.0f/2048.0f)

typedef unsigned short u16;
typedef __bf16 bf16x8 __attribute__((ext_vector_type(8)));
typedef u16   u16x8  __attribute__((ext_vector_type(8)));
typedef u16   u16x4  __attribute__((ext_vector_type(4)));
typedef float f32x4  __attribute__((ext_vector_type(4)));

__device__ __forceinline__ u16 f2bf(float f) {
  union { float f; uint32_t u; } v; v.f = f;
  uint32_t r = v.u + 0x7FFFu + ((v.u >> 16) & 1u);   // RNE
  return (u16)(r >> 16);
}
__device__ __forceinline__ u16 f2bfc(float f) {     // compiler cast (packs to cvt_pk)
  return __builtin_bit_cast(u16, (__bf16)f);
}
__device__ __forceinline__ float bf2f(u16 b) {
  union { uint32_t u; float f; } v; v.u = ((uint32_t)b) << 16;
  return v.f;
}
__device__ __forceinline__ bf16x8 ldb(const u16* p) {
  u16x8 r = *(const u16x8*)p;
  return __builtin_bit_cast(bf16x8, r);
}
#define MFMA16(a,b,c) __builtin_amdgcn_mfma_f32_16x16x32_bf16((a),(b),(c),0,0,0)

// precise silu — attn feeds LayerNorm (rsqrt(var) amplifies perturbations);
// v_rcp variant measurably pushed absmax 0.031 -> 0.125 (round 6). Keep exact.
__device__ __forceinline__ float silu_f(float s) {
  return s / (1.0f + __expf(-s));
}

// async global->LDS, 16B per lane; lds base must be wave-uniform
__device__ __forceinline__ void gload16(const u16* g, u16* lds) {
  __builtin_amdgcn_global_load_lds(
      (const __attribute__((address_space(1))) void*)g,
      (__attribute__((address_space(3))) void*)lds, 16, 0, 0);
}

// ---------------- cast / transpose weights ----------------
__global__ __launch_bounds__(256) void k_cast_uvqk(const float* __restrict__ in,
                                                   u16* __restrict__ out) {
  __shared__ float tile[32][33];
  int tx = threadIdx.x & 31, ty = threadIdx.x >> 5;
  int j0 = blockIdx.x * 32;
  int k0 = blockIdx.y * 32;
#pragma unroll
  for (int r = ty; r < 32; r += 8)
    tile[r][tx] = in[(size_t)(k0 + r) * EDIM + j0 + tx];
  __syncthreads();
#pragma unroll
  for (int r = ty; r < 32; r += 8)
    out[(size_t)(j0 + r) * DIM + k0 + tx] = f2bf(tile[tx][r]);
}

__global__ __launch_bounds__(256) void k_cast_ow(const float* __restrict__ in,
                                                 u16* __restrict__ out) {
  int i = blockIdx.x * 256 + threadIdx.x;
  out[i] = f2bf(in[i]);
}

// ---------------- LayerNorm(x) -> bf16 ----------------
__global__ __launch_bounds__(256) void k_ln1(const float* __restrict__ x,
                                             u16* __restrict__ xn) {
  int lane = threadIdx.x & 63, wid = threadIdx.x >> 6;
  size_t row = (size_t)blockIdx.x * 4 + wid;
  const float* xr = x + row * DIM;
  float4 a = ((const float4*)xr)[lane * 2];
  float4 b = ((const float4*)xr)[lane * 2 + 1];
  float s = a.x + a.y + a.z + a.w + b.x + b.y + b.z + b.w;
#pragma unroll
  for (int o = 32; o; o >>= 1) s += __shfl_xor(s, o);
  float mu = s * (1.0f / DIM);
  float d[8] = {a.x - mu, a.y - mu, a.z - mu, a.w - mu,
                b.x - mu, b.y - mu, b.z - mu, b.w - mu};
  float v = 0.f;
#pragma unroll
  for (int j = 0; j < 8; ++j) v += d[j] * d[j];
#pragma unroll
  for (int o = 32; o; o >>= 1) v += __shfl_xor(v, o);
  float rs = rsqrtf(v * (1.0f / DIM) + 1e-6f);
  u16x8 o8;
#pragma unroll
  for (int j = 0; j < 8; ++j) o8[j] = f2bf(d[j] * rs);
  *(u16x8*)(xn + row * DIM + lane * 8) = o8;
}

// ---------------- GEMM1 (m97 structure): proj = silu(xn @ uvqk) ----------------
__global__ __launch_bounds__(256) void k_gemm1(const u16* __restrict__ A,
                                               const u16* __restrict__ Bt,
                                               u16* __restrict__ P) {
  __shared__ u16 As[128 * 64];
  __shared__ u16 Bs[128 * 64];
  int tid = threadIdx.x, lane = tid & 63, wid = tid >> 6;
  int lm = lane & 15, lg = lane >> 4;
  int wr = wid >> 1, wc = wid & 1;
  int r0 = blockIdx.y * 128;
  int c0 = blockIdx.x * 128;

  int srow = wid * 8 + (lane >> 3);
  int scol = (lane & 7) * 8;

  f32x4 acc[4][4];
  f32x4 z = {0.f, 0.f, 0.f, 0.f};
#pragma unroll
  for (int mt = 0; mt < 4; ++mt)
#pragma unroll
    for (int nt = 0; nt < 4; ++nt) acc[mt][nt] = z;

  for (int ks = 0; ks < DIM / 64; ++ks) {
#pragma unroll
    for (int it = 0; it < 4; ++it) {
      gload16(A + (size_t)(r0 + it * 32 + srow) * DIM + ks * 64 + scol,
              As + it * 2048 + wid * 512);
      gload16(Bt + (size_t)(c0 + it * 32 + srow) * DIM + ks * 64 + scol,
              Bs + it * 2048 + wid * 512);
    }
    __syncthreads();

#pragma unroll
    for (int kk = 0; kk < 2; ++kk) {
      bf16x8 am[4], bn[4];
#pragma unroll
      for (int mt = 0; mt < 4; ++mt)
        am[mt] = ldb(&As[(wr * 64 + mt * 16 + lm) * 64 + kk * 32 + lg * 8]);
#pragma unroll
      for (int nt = 0; nt < 4; ++nt)
        bn[nt] = ldb(&Bs[(wc * 64 + nt * 16 + lm) * 64 + kk * 32 + lg * 8]);
#pragma unroll
      for (int mt = 0; mt < 4; ++mt)
#pragma unroll
        for (int nt = 0; nt < 4; ++nt)
          acc[mt][nt] = MFMA16(am[mt], bn[nt], acc[mt][nt]);
    }
    __syncthreads();
  }

#pragma unroll
  for (int mt = 0; mt < 4; ++mt)
#pragma unroll
    for (int nt = 0; nt < 4; ++nt)
#pragma unroll
      for (int i = 0; i < 4; ++i) {
        size_t row = r0 + wr * 64 + mt * 16 + lg * 4 + i;
        int col = c0 + wc * 64 + nt * 16 + lm;
        P[row * EDIM + col] = f2bf(silu_f(acc[mt][nt][i]));
      }
}

// ---------------- V^T transpose: vt[bh][e 64][n 2048] ----------------
__global__ __launch_bounds__(256) void k_vt(const u16* __restrict__ proj,
                                            u16* __restrict__ vt) {
  __shared__ u16 t[64][72];
  int tid = threadIdx.x;
  int bh = blockIdx.y, b = bh >> 3, h = bh & 7;
  int n0 = blockIdx.x * 64;
#pragma unroll
  for (int it = 0; it < 2; ++it) {
    int row = it * 32 + (tid >> 3), col = (tid & 7) * 8;
    *(u16x8*)&t[row][col] =
        *(const u16x8*)(proj + (size_t)(b * NTOK + n0 + row) * EDIM + 512 + h * 64 + col);
  }
  __syncthreads();
#pragma unroll
  for (int it = 0; it < 2; ++it) {
    int erow = it * 32 + (tid >> 3), ncol = (tid & 7) * 8;
    u16x8 o;
#pragma unroll
    for (int j = 0; j < 8; ++j) o[j] = t[ncol + j][erow];
    *(u16x8*)(vt + ((size_t)bh * 64 + erow) * NTOK + n0 + ncol) = o;
  }
}

// ---------------- HSTU attention v5b ----------------
// 1024 blocks: one 64-row q-tile each, LPT (descending qtile) + XCD-chunked.
// 40KB LDS/block -> 4 blocks/CU; dynamic refill rebalances causal skew.
// Swapped QK^T (S^T in acc), swizzled p_lds, double-buffered K/V^T staging.
// silu kept PRECISE (LN2 downstream amplifies attn perturbations).
__global__ __launch_bounds__(256) void k_attn(const u16* __restrict__ proj,
                                              const u16* __restrict__ vt,
                                              float* __restrict__ attn) {
  __shared__ u16 kv0[8192];                 // K[64][64] | V^T[64][64]  16KB
  __shared__ u16 kv1[8192];                 // 16KB
  __shared__ u16 p_lds[4][16][64];          // per-wave P[q 16][m 64], XOR-swizzled, 8KB
  int tid = threadIdx.x, lane = tid & 63, w = tid >> 6;
  int lm = lane & 15, lg = lane >> 4;

  // XCD-chunked remap: 4 heads per XCD (2MB K+V^T in its L2); LPT within XCD.
  int bid = blockIdx.x;                     // 0..1023
  int xcd = bid & 7, idx = bid >> 3;        // idx 0..127
  int qtile = 31 - (idx >> 2);              // descending work (LPT)
  int bh = (xcd << 2) + (idx & 3);          // 0..31
  int b = bh >> 3, h = bh & 7;
  int n0 = qtile * 64;
  int nrow = n0 + w * 16;                   // wave's first q row
  int nlm = nrow + lm;                      // this lane's q (column of S^T)

  const u16* pb = proj + (size_t)b * NTOK * EDIM;
  const u16* kb = pb + 1536 + h * 64;
  const u16* vb = vt + (size_t)bh * 64 * NTOK;

  f32x4 z = {0.f, 0.f, 0.f, 0.f};

  // staging: lane l covers LDS row base+(l>>3), phys 16B slot (l&7);
  // source col pre-swizzled so read with col^((row&7)<<3) is linear data.
  int sr = lane >> 3;
  int sc = ((lane & 7) ^ sr) * 8;           // u16 units
  const u16* ks0 = kb + (size_t)(w * 16 + sr) * EDIM + sc;
  const u16* ks1 = kb + (size_t)(w * 16 + 8 + sr) * EDIM + sc;
  const u16* vs0 = vb + (size_t)(w * 16 + sr) * NTOK + sc;
  const u16* vs1 = vb + (size_t)(w * 16 + 8 + sr) * NTOK + sc;

  const u16* qrow = pb + (size_t)nlm * EDIM + 1024 + h * 64 + lg * 8;
  bf16x8 qf0 = ldb(qrow), qf1 = ldb(qrow + 32);

  f32x4 acc[4];
#pragma unroll
  for (int et = 0; et < 4; ++et) acc[et] = z;

  int psw = (lm & 7) << 3;                  // p_lds XOR swizzle for this lane

  // prologue: stage tile 0 -> kv0
  gload16(ks0, kv0 + (w * 16) * 64);
  gload16(ks1, kv0 + (w * 16 + 8) * 64);
  gload16(vs0, kv0 + 4096 + (w * 16) * 64);
  gload16(vs1, kv0 + 4096 + (w * 16 + 8) * 64);
  asm volatile("s_waitcnt vmcnt(0)" ::: "memory");
  __builtin_amdgcn_s_barrier();

  int ntl = qtile + 1;
  for (int t = 0; t < ntl; ++t) {
    const u16* kt = (t & 1) ? kv1 : kv0;
    const u16* vl = kt + 4096;
    if (t + 1 < ntl) {                      // prefetch next tile
      u16* kd = ((t + 1) & 1) ? kv1 : kv0;
      size_t ko = (size_t)(t + 1) * 64 * EDIM;
      size_t vo = (size_t)(t + 1) * 64;
      gload16(ks0 + ko, kd + (w * 16) * 64);
      gload16(ks1 + ko, kd + (w * 16 + 8) * 64);
      gload16(vs0 + vo, kd + 4096 + (w * 16) * 64);
      gload16(vs1 + vo, kd + 4096 + (w * 16 + 8) * 64);
    }
    // ---- QK^T swapped: S^T[m][q]; K as A-frag (same lane map as B-frag)
    bf16x8 kf[4][2];
#pragma unroll
    for (int mb = 0; mb < 4; ++mb)
#pragma unroll
      for (int kk = 0; kk < 2; ++kk)
        kf[mb][kk] = ldb(&kt[(mb * 16 + lm) * 64 +
                             ((kk * 32 + lg * 8) ^ ((lm & 7) << 3))]);
    if (t == qtile) {                       // diagonal tile: masked (wave-uniform)
#pragma unroll
      for (int mb = 0; mb < 4; ++mb) {
        f32x4 s = MFMA16(kf[mb][0], qf0, z);
        s = MFMA16(kf[mb][1], qf1, s);
        int m = t * 64 + mb * 16 + lg * 4;
        u16x4 pk;
#pragma unroll
        for (int i = 0; i < 4; ++i)
          pk[i] = (m + i <= nlm) ? f2bfc(silu_f(s[i])) : (u16)0;
        *(u16x4*)&p_lds[w][lm][(mb * 16 + lg * 4) ^ psw] = pk;
      }
    } else {                                // full tile: no mask
#pragma unroll
      for (int mb = 0; mb < 4; ++mb) {
        f32x4 s = MFMA16(kf[mb][0], qf0, z);
        s = MFMA16(kf[mb][1], qf1, s);
        u16x4 pk;
#pragma unroll
        for (int i = 0; i < 4; ++i) pk[i] = f2bfc(silu_f(s[i]));
        *(u16x4*)&p_lds[w][lm][(mb * 16 + lg * 4) ^ psw] = pk;
      }
    }
    // ---- PV: A = P (rows q, k=m), B = V^T frag
    bf16x8 vf[2][4];
#pragma unroll
    for (int kk = 0; kk < 2; ++kk)
#pragma unroll
      for (int et = 0; et < 4; ++et)
        vf[kk][et] = ldb(&vl[(et * 16 + lm) * 64 +
                             ((kk * 32 + lg * 8) ^ ((lm & 7) << 3))]);
    bf16x8 pf0 = ldb(&p_lds[w][lm][(lg * 8) ^ psw]);
    bf16x8 pf1 = ldb(&p_lds[w][lm][(32 + lg * 8) ^ psw]);
#pragma unroll
    for (int et = 0; et < 4; ++et) {
      acc[et] = MFMA16(pf0, vf[0][et], acc[et]);
      acc[et] = MFMA16(pf1, vf[1][et], acc[et]);
    }
    asm volatile("s_waitcnt vmcnt(0)" ::: "memory");
    __builtin_amdgcn_s_barrier();
  }

#pragma unroll
  for (int et = 0; et < 4; ++et)
#pragma unroll
    for (int i = 0; i < 4; ++i)
      attn[((size_t)b * NTOK + nrow + lg * 4 + i) * DIM +
           h * 64 + et * 16 + lm] = acc[et][i] * INV_N;
}

// ---------------- LN(attn) * u -> bf16 ----------------
__global__ __launch_bounds__(256) void k_ln2(const float* __restrict__ attn,
                                             const u16* __restrict__ proj,
                                             u16* __restrict__ o_in) {
  int lane = threadIdx.x & 63, wid = threadIdx.x >> 6;
  size_t row = (size_t)blockIdx.x * 4 + wid;
  const float* ar = attn + row * DIM;
  float4 a = ((const float4*)ar)[lane * 2];
  float4 b = ((const float4*)ar)[lane * 2 + 1];
  float s = a.x + a.y + a.z + a.w + b.x + b.y + b.z + b.w;
#pragma unroll
  for (int o = 32; o; o >>= 1) s += __shfl_xor(s, o);
  float mu = s * (1.0f / DIM);
  float d[8] = {a.x - mu, a.y - mu, a.z - mu, a.w - mu,
                b.x - mu, b.y - mu, b.z - mu, b.w - mu};
  float v = 0.f;
#pragma unroll
  for (int j = 0; j < 8; ++j) v += d[j] * d[j];
#pragma unroll
  for (int o = 32; o; o >>= 1) v += __shfl_xor(v, o);
  float rs = rsqrtf(v * (1.0f / DIM) + 1e-6f);
  u16x8 u8 = *(const u16x8*)(proj + row * EDIM + lane * 8);
  u16x8 o8;
#pragma unroll
  for (int j = 0; j < 8; ++j) o8[j] = f2bf(bf2f(u8[j]) * (d[j] * rs));
  *(u16x8*)(o_in + row * DIM + lane * 8) = o8;
}

// ---------------- GEMM2: out = o_in @ o_w^T + o_b + x ----------------
__global__ __launch_bounds__(256) void k_gemm2(const u16* __restrict__ A,
                                               const u16* __restrict__ Bw,
                                               const float* __restrict__ o_b,
                                               const float* __restrict__ x,
                                               float* __restrict__ out) {
  int lane = threadIdx.x & 63, wid = threadIdx.x >> 6;
  int lm = lane & 15, lg = lane >> 4;
  int r0 = blockIdx.y * 64 + wid * 16;
  int c0 = blockIdx.x * 64;
  const u16* ap = A + (size_t)(r0 + lm) * DIM + lg * 8;
  const u16* bp = Bw + (size_t)(c0 + lm) * DIM + lg * 8;
  f32x4 acc[4];
  f32x4 z = {0.f, 0.f, 0.f, 0.f};
#pragma unroll
  for (int jt = 0; jt < 4; ++jt) acc[jt] = z;
#pragma unroll 4
  for (int k0 = 0; k0 < DIM; k0 += 32) {
    bf16x8 af = ldb(ap + k0);
#pragma unroll
    for (int jt = 0; jt < 4; ++jt)
      acc[jt] = MFMA16(af, ldb(bp + (size_t)jt * 16 * DIM + k0), acc[jt]);
  }
#pragma unroll
  for (int jt = 0; jt < 4; ++jt)
#pragma unroll
    for (int i = 0; i < 4; ++i) {
      size_t row = r0 + lg * 4 + i;
      int col = c0 + jt * 16 + lm;
      out[row * DIM + col] = acc[jt][i] + o_b[col] + x[row * DIM + col];
    }
}

extern "C" void kernel_launch(void* const* d_in, const int* in_sizes, int n_in,
                              void* d_out, int out_size, void* d_ws, size_t ws_size,
                              hipStream_t stream) {
  const float* x    = (const float*)d_in[0];
  // d_in[1] = invalid_attn_mask: structurally causal tril; applied as predicate.
  const float* uvqk = (const float*)d_in[2];
  const float* o_w  = (const float*)d_in[3];
  const float* o_b  = (const float*)d_in[4];
  float* out = (float*)d_out;

  u16* uvqk_t = (u16*)d_ws;                         // [2048][512] bf16   2MB
  u16* ow_bf  = uvqk_t + (size_t)EDIM * DIM;        // [512][512]  bf16   0.5MB
  u16* xn     = ow_bf + (size_t)DIM * DIM;          // [8192][512] bf16   8MB
  u16* proj   = xn + (size_t)BNROWS * DIM;          // [8192][2048] bf16  32MB
  float* attn = (float*)(proj + (size_t)BNROWS * EDIM); // [8192][512] f32 16MB
  u16* o_in   = (u16*)(attn + (size_t)BNROWS * DIM);    // [8192][512] bf16 8MB
  u16* vt     = o_in + (size_t)BNROWS * DIM;            // [32][64][2048] bf16 8MB

  k_cast_uvqk<<<dim3(64, 16), 256, 0, stream>>>(uvqk, uvqk_t);
  k_cast_ow<<<dim3(1024), 256, 0, stream>>>(o_w, ow_bf);
  k_ln1<<<dim3(2048), 256, 0, stream>>>(x, xn);
  k_gemm1<<<dim3(16, 64), 256, 0, stream>>>(xn, uvqk_t, proj);
  k_vt<<<dim3(32, 32), 256, 0, stream>>>(proj, vt);
  k_attn<<<dim3(1024), 256, 0, stream>>>(proj, vt, attn);
  k_ln2<<<dim3(2048), 256, 0, stream>>>(attn, proj, o_in);
  k_gemm2<<<dim3(8, 128), 256, 0, stream>>>(o_in, ow_bf, o_b, x, out);
}

// Round 8
// 150.492 us; speedup vs baseline: 2.3530x; 1.0150x over previous
//
#include <hip/hip_runtime.h>
#include <cstdint>

#define NTOK 2048
#define DIM 512
#define EDIM 2048
#define BATCH 4
#define HEADS 8
#define BNROWS 8192   /* B*N */
#define INV_N (1.0f/2048.0f)

typedef unsigned short u16;
typedef __bf16 bf16x8 __attribute__((ext_vector_type(8)));
typedef u16   u16x8  __attribute__((ext_vector_type(8)));
typedef u16   u16x4  __attribute__((ext_vector_type(4)));
typedef float f32x4  __attribute__((ext_vector_type(4)));

__device__ __forceinline__ u16 f2bf(float f) {
  union { float f; uint32_t u; } v; v.f = f;
  uint32_t r = v.u + 0x7FFFu + ((v.u >> 16) & 1u);   // RNE
  return (u16)(r >> 16);
}
__device__ __forceinline__ u16 f2bfc(float f) {     // compiler cast (packs to cvt_pk)
  return __builtin_bit_cast(u16, (__bf16)f);
}
__device__ __forceinline__ float bf2f(u16 b) {
  union { uint32_t u; float f; } v; v.u = ((uint32_t)b) << 16;
  return v.f;
}
__device__ __forceinline__ bf16x8 ldb(const u16* p) {
  u16x8 r = *(const u16x8*)p;
  return __builtin_bit_cast(bf16x8, r);
}
#define MFMA16(a,b,c) __builtin_amdgcn_mfma_f32_16x16x32_bf16((a),(b),(c),0,0,0)

// precise silu — attn feeds LayerNorm (rsqrt(var) amplifies perturbations);
// v_rcp variant measurably pushed absmax 0.031 -> 0.125 (round 6). Keep exact.
__device__ __forceinline__ float silu_f(float s) {
  return s / (1.0f + __expf(-s));
}

// async global->LDS, 16B per lane; lds base must be wave-uniform
__device__ __forceinline__ void gload16(const u16* g, u16* lds) {
  __builtin_amdgcn_global_load_lds(
      (const __attribute__((address_space(1))) void*)g,
      (__attribute__((address_space(3))) void*)lds, 16, 0, 0);
}

// ---------------- cast / transpose weights ----------------
__global__ __launch_bounds__(256) void k_cast_uvqk(const float* __restrict__ in,
                                                   u16* __restrict__ out) {
  __shared__ float tile[32][33];
  int tx = threadIdx.x & 31, ty = threadIdx.x >> 5;
  int j0 = blockIdx.x * 32;
  int k0 = blockIdx.y * 32;
#pragma unroll
  for (int r = ty; r < 32; r += 8)
    tile[r][tx] = in[(size_t)(k0 + r) * EDIM + j0 + tx];
  __syncthreads();
#pragma unroll
  for (int r = ty; r < 32; r += 8)
    out[(size_t)(j0 + r) * DIM + k0 + tx] = f2bf(tile[tx][r]);
}

__global__ __launch_bounds__(256) void k_cast_ow(const float* __restrict__ in,
                                                 u16* __restrict__ out) {
  int i = blockIdx.x * 256 + threadIdx.x;
  out[i] = f2bf(in[i]);
}

// ---------------- LayerNorm(x) -> bf16 ----------------
__global__ __launch_bounds__(256) void k_ln1(const float* __restrict__ x,
                                             u16* __restrict__ xn) {
  int lane = threadIdx.x & 63, wid = threadIdx.x >> 6;
  size_t row = (size_t)blockIdx.x * 4 + wid;
  const float* xr = x + row * DIM;
  float4 a = ((const float4*)xr)[lane * 2];
  float4 b = ((const float4*)xr)[lane * 2 + 1];
  float s = a.x + a.y + a.z + a.w + b.x + b.y + b.z + b.w;
#pragma unroll
  for (int o = 32; o; o >>= 1) s += __shfl_xor(s, o);
  float mu = s * (1.0f / DIM);
  float d[8] = {a.x - mu, a.y - mu, a.z - mu, a.w - mu,
                b.x - mu, b.y - mu, b.z - mu, b.w - mu};
  float v = 0.f;
#pragma unroll
  for (int j = 0; j < 8; ++j) v += d[j] * d[j];
#pragma unroll
  for (int o = 32; o; o >>= 1) v += __shfl_xor(v, o);
  float rs = rsqrtf(v * (1.0f / DIM) + 1e-6f);
  u16x8 o8;
#pragma unroll
  for (int j = 0; j < 8; ++j) o8[j] = f2bf(d[j] * rs);
  *(u16x8*)(xn + row * DIM + lane * 8) = o8;
}

// ---------------- GEMM1: proj = silu(xn @ uvqk), fused vt write ----------------
// XCD-chunked 1D grid: each XCD owns 8 row-panels x 16 col-blocks
// (A 1MB + B 2MB < 4MB L2). For v-slice col-blocks (cols 512..1024) the
// epilogue also emits vt[bh][e][n] (bit-identical bf16, 1 b64 store per frag).
__global__ __launch_bounds__(256) void k_gemm1(const u16* __restrict__ A,
                                               const u16* __restrict__ Bt,
                                               u16* __restrict__ P,
                                               u16* __restrict__ vt) {
  __shared__ u16 As[128 * 64];
  __shared__ u16 Bs[128 * 64];
  int tid = threadIdx.x, lane = tid & 63, wid = tid >> 6;
  int lm = lane & 15, lg = lane >> 4;
  int wr = wid >> 1, wc = wid & 1;

  int bid = blockIdx.x;                 // 0..1023
  int xcd = bid & 7, idx = bid >> 3;
  int orig = xcd * 128 + idx;           // 128 contiguous work-items per XCD
  int r0 = (orig >> 4) * 128;           // row-panel (8 per XCD)
  int c0 = (orig & 15) * 128;           // col-block

  int srow = wid * 8 + (lane >> 3);
  int scol = (lane & 7) * 8;

  f32x4 acc[4][4];
  f32x4 z = {0.f, 0.f, 0.f, 0.f};
#pragma unroll
  for (int mt = 0; mt < 4; ++mt)
#pragma unroll
    for (int nt = 0; nt < 4; ++nt) acc[mt][nt] = z;

  for (int ks = 0; ks < DIM / 64; ++ks) {
#pragma unroll
    for (int it = 0; it < 4; ++it) {
      gload16(A + (size_t)(r0 + it * 32 + srow) * DIM + ks * 64 + scol,
              As + it * 2048 + wid * 512);
      gload16(Bt + (size_t)(c0 + it * 32 + srow) * DIM + ks * 64 + scol,
              Bs + it * 2048 + wid * 512);
    }
    __syncthreads();

#pragma unroll
    for (int kk = 0; kk < 2; ++kk) {
      bf16x8 am[4], bn[4];
#pragma unroll
      for (int mt = 0; mt < 4; ++mt)
        am[mt] = ldb(&As[(wr * 64 + mt * 16 + lm) * 64 + kk * 32 + lg * 8]);
#pragma unroll
      for (int nt = 0; nt < 4; ++nt)
        bn[nt] = ldb(&Bs[(wc * 64 + nt * 16 + lm) * 64 + kk * 32 + lg * 8]);
#pragma unroll
      for (int mt = 0; mt < 4; ++mt)
#pragma unroll
        for (int nt = 0; nt < 4; ++nt)
          acc[mt][nt] = MFMA16(am[mt], bn[nt], acc[mt][nt]);
    }
    __syncthreads();
  }

  bool isv = (c0 >= 512) && (c0 < 1024);
  int btc = r0 >> 11;                   // batch index
  int nbw = (r0 & 2047) + wr * 64;      // n base for this wave
  int hv  = ((c0 - 512) >> 6) + wc;     // head (valid when isv)

#pragma unroll
  for (int mt = 0; mt < 4; ++mt)
#pragma unroll
    for (int nt = 0; nt < 4; ++nt) {
      u16 pv[4];
#pragma unroll
      for (int i = 0; i < 4; ++i) {
        size_t row = r0 + wr * 64 + mt * 16 + lg * 4 + i;
        int col = c0 + wc * 64 + nt * 16 + lm;
        pv[i] = f2bf(silu_f(acc[mt][nt][i]));
        P[row * EDIM + col] = pv[i];
      }
      if (isv) {
        int e = nt * 16 + lm;
        int n = nbw + mt * 16 + lg * 4;
        u16x4 pk = {pv[0], pv[1], pv[2], pv[3]};
        *(u16x4*)(vt + ((size_t)(btc * 8 + hv) * 64 + e) * NTOK + n) = pk;
      }
    }
}

// ---------------- HSTU attention v5b ----------------
// 1024 blocks: one 64-row q-tile each, LPT (descending qtile) + XCD-chunked.
// 40KB LDS/block -> 4 blocks/CU. Swapped QK^T (S^T in acc), swizzled p_lds,
// double-buffered K/V^T staging. silu kept PRECISE (LN2 amplifies).
__global__ __launch_bounds__(256) void k_attn(const u16* __restrict__ proj,
                                              const u16* __restrict__ vt,
                                              float* __restrict__ attn) {
  __shared__ u16 kv0[8192];                 // K[64][64] | V^T[64][64]  16KB
  __shared__ u16 kv1[8192];                 // 16KB
  __shared__ u16 p_lds[4][16][64];          // per-wave P[q 16][m 64], XOR-swizzled, 8KB
  int tid = threadIdx.x, lane = tid & 63, w = tid >> 6;
  int lm = lane & 15, lg = lane >> 4;

  // XCD-chunked remap: 4 heads per XCD (2MB K+V^T in its L2); LPT within XCD.
  int bid = blockIdx.x;                     // 0..1023
  int xcd = bid & 7, idx = bid >> 3;        // idx 0..127
  int qtile = 31 - (idx >> 2);              // descending work (LPT)
  int bh = (xcd << 2) + (idx & 3);          // 0..31
  int b = bh >> 3, h = bh & 7;
  int n0 = qtile * 64;
  int nrow = n0 + w * 16;                   // wave's first q row
  int nlm = nrow + lm;                      // this lane's q (column of S^T)

  const u16* pb = proj + (size_t)b * NTOK * EDIM;
  const u16* kb = pb + 1536 + h * 64;
  const u16* vb = vt + (size_t)bh * 64 * NTOK;

  f32x4 z = {0.f, 0.f, 0.f, 0.f};

  // staging: lane l covers LDS row base+(l>>3), phys 16B slot (l&7);
  // source col pre-swizzled so read with col^((row&7)<<3) is linear data.
  int sr = lane >> 3;
  int sc = ((lane & 7) ^ sr) * 8;           // u16 units
  const u16* ks0 = kb + (size_t)(w * 16 + sr) * EDIM + sc;
  const u16* ks1 = kb + (size_t)(w * 16 + 8 + sr) * EDIM + sc;
  const u16* vs0 = vb + (size_t)(w * 16 + sr) * NTOK + sc;
  const u16* vs1 = vb + (size_t)(w * 16 + 8 + sr) * NTOK + sc;

  const u16* qrow = pb + (size_t)nlm * EDIM + 1024 + h * 64 + lg * 8;
  bf16x8 qf0 = ldb(qrow), qf1 = ldb(qrow + 32);

  f32x4 acc[4];
#pragma unroll
  for (int et = 0; et < 4; ++et) acc[et] = z;

  int psw = (lm & 7) << 3;                  // p_lds XOR swizzle for this lane

  // prologue: stage tile 0 -> kv0
  gload16(ks0, kv0 + (w * 16) * 64);
  gload16(ks1, kv0 + (w * 16 + 8) * 64);
  gload16(vs0, kv0 + 4096 + (w * 16) * 64);
  gload16(vs1, kv0 + 4096 + (w * 16 + 8) * 64);
  asm volatile("s_waitcnt vmcnt(0)" ::: "memory");
  __builtin_amdgcn_s_barrier();

  int ntl = qtile + 1;
  for (int t = 0; t < ntl; ++t) {
    const u16* kt = (t & 1) ? kv1 : kv0;
    const u16* vl = kt + 4096;
    if (t + 1 < ntl) {                      // prefetch next tile
      u16* kd = ((t + 1) & 1) ? kv1 : kv0;
      size_t ko = (size_t)(t + 1) * 64 * EDIM;
      size_t vo = (size_t)(t + 1) * 64;
      gload16(ks0 + ko, kd + (w * 16) * 64);
      gload16(ks1 + ko, kd + (w * 16 + 8) * 64);
      gload16(vs0 + vo, kd + 4096 + (w * 16) * 64);
      gload16(vs1 + vo, kd + 4096 + (w * 16 + 8) * 64);
    }
    // ---- QK^T swapped: S^T[m][q]; K as A-frag (same lane map as B-frag)
    bf16x8 kf[4][2];
#pragma unroll
    for (int mb = 0; mb < 4; ++mb)
#pragma unroll
      for (int kk = 0; kk < 2; ++kk)
        kf[mb][kk] = ldb(&kt[(mb * 16 + lm) * 64 +
                             ((kk * 32 + lg * 8) ^ ((lm & 7) << 3))]);
    if (t == qtile) {                       // diagonal tile: masked (wave-uniform)
#pragma unroll
      for (int mb = 0; mb < 4; ++mb) {
        f32x4 s = MFMA16(kf[mb][0], qf0, z);
        s = MFMA16(kf[mb][1], qf1, s);
        int m = t * 64 + mb * 16 + lg * 4;
        u16x4 pk;
#pragma unroll
        for (int i = 0; i < 4; ++i)
          pk[i] = (m + i <= nlm) ? f2bfc(silu_f(s[i])) : (u16)0;
        *(u16x4*)&p_lds[w][lm][(mb * 16 + lg * 4) ^ psw] = pk;
      }
    } else {                                // full tile: no mask
#pragma unroll
      for (int mb = 0; mb < 4; ++mb) {
        f32x4 s = MFMA16(kf[mb][0], qf0, z);
        s = MFMA16(kf[mb][1], qf1, s);
        u16x4 pk;
#pragma unroll
        for (int i = 0; i < 4; ++i) pk[i] = f2bfc(silu_f(s[i]));
        *(u16x4*)&p_lds[w][lm][(mb * 16 + lg * 4) ^ psw] = pk;
      }
    }
    // ---- PV: A = P (rows q, k=m), B = V^T frag
    bf16x8 vf[2][4];
#pragma unroll
    for (int kk = 0; kk < 2; ++kk)
#pragma unroll
      for (int et = 0; et < 4; ++et)
        vf[kk][et] = ldb(&vl[(et * 16 + lm) * 64 +
                             ((kk * 32 + lg * 8) ^ ((lm & 7) << 3))]);
    bf16x8 pf0 = ldb(&p_lds[w][lm][(lg * 8) ^ psw]);
    bf16x8 pf1 = ldb(&p_lds[w][lm][(32 + lg * 8) ^ psw]);
#pragma unroll
    for (int et = 0; et < 4; ++et) {
      acc[et] = MFMA16(pf0, vf[0][et], acc[et]);
      acc[et] = MFMA16(pf1, vf[1][et], acc[et]);
    }
    asm volatile("s_waitcnt vmcnt(0)" ::: "memory");
    __builtin_amdgcn_s_barrier();
  }

#pragma unroll
  for (int et = 0; et < 4; ++et)
#pragma unroll
    for (int i = 0; i < 4; ++i)
      attn[((size_t)b * NTOK + nrow + lg * 4 + i) * DIM +
           h * 64 + et * 16 + lm] = acc[et][i] * INV_N;
}

// ---------------- LN(attn) * u -> bf16 ----------------
__global__ __launch_bounds__(256) void k_ln2(const float* __restrict__ attn,
                                             const u16* __restrict__ proj,
                                             u16* __restrict__ o_in) {
  int lane = threadIdx.x & 63, wid = threadIdx.x >> 6;
  size_t row = (size_t)blockIdx.x * 4 + wid;
  const float* ar = attn + row * DIM;
  float4 a = ((const float4*)ar)[lane * 2];
  float4 b = ((const float4*)ar)[lane * 2 + 1];
  float s = a.x + a.y + a.z + a.w + b.x + b.y + b.z + b.w;
#pragma unroll
  for (int o = 32; o; o >>= 1) s += __shfl_xor(s, o);
  float mu = s * (1.0f / DIM);
  float d[8] = {a.x - mu, a.y - mu, a.z - mu, a.w - mu,
                b.x - mu, b.y - mu, b.z - mu, b.w - mu};
  float v = 0.f;
#pragma unroll
  for (int j = 0; j < 8; ++j) v += d[j] * d[j];
#pragma unroll
  for (int o = 32; o; o >>= 1) v += __shfl_xor(v, o);
  float rs = rsqrtf(v * (1.0f / DIM) + 1e-6f);
  u16x8 u8 = *(const u16x8*)(proj + row * EDIM + lane * 8);
  u16x8 o8;
#pragma unroll
  for (int j = 0; j < 8; ++j) o8[j] = f2bf(bf2f(u8[j]) * (d[j] * rs));
  *(u16x8*)(o_in + row * DIM + lane * 8) = o8;
}

// ---------------- GEMM2: out = o_in @ o_w^T + o_b + x ----------------
// XCD-chunked 1D grid: 16 row-panels x 8 col-blocks per XCD (A-panel L2-local).
__global__ __launch_bounds__(256) void k_gemm2(const u16* __restrict__ A,
                                               const u16* __restrict__ Bw,
                                               const float* __restrict__ o_b,
                                               const float* __restrict__ x,
                                               float* __restrict__ out) {
  int lane = threadIdx.x & 63, wid = threadIdx.x >> 6;
  int lm = lane & 15, lg = lane >> 4;

  int bid = blockIdx.x;                 // 0..1023
  int xcd = bid & 7, idx = bid >> 3;
  int orig = xcd * 128 + idx;
  int r0 = (orig >> 3) * 64 + wid * 16;
  int c0 = (orig & 7) * 64;

  const u16* ap = A + (size_t)(r0 + lm) * DIM + lg * 8;
  const u16* bp = Bw + (size_t)(c0 + lm) * DIM + lg * 8;
  f32x4 acc[4];
  f32x4 z = {0.f, 0.f, 0.f, 0.f};
#pragma unroll
  for (int jt = 0; jt < 4; ++jt) acc[jt] = z;
#pragma unroll 4
  for (int k0 = 0; k0 < DIM; k0 += 32) {
    bf16x8 af = ldb(ap + k0);
#pragma unroll
    for (int jt = 0; jt < 4; ++jt)
      acc[jt] = MFMA16(af, ldb(bp + (size_t)jt * 16 * DIM + k0), acc[jt]);
  }
#pragma unroll
  for (int jt = 0; jt < 4; ++jt)
#pragma unroll
    for (int i = 0; i < 4; ++i) {
      size_t row = r0 + lg * 4 + i;
      int col = c0 + jt * 16 + lm;
      out[row * DIM + col] = acc[jt][i] + o_b[col] + x[row * DIM + col];
    }
}

extern "C" void kernel_launch(void* const* d_in, const int* in_sizes, int n_in,
                              void* d_out, int out_size, void* d_ws, size_t ws_size,
                              hipStream_t stream) {
  const float* x    = (const float*)d_in[0];
  // d_in[1] = invalid_attn_mask: structurally causal tril; applied as predicate.
  const float* uvqk = (const float*)d_in[2];
  const float* o_w  = (const float*)d_in[3];
  const float* o_b  = (const float*)d_in[4];
  float* out = (float*)d_out;

  u16* uvqk_t = (u16*)d_ws;                         // [2048][512] bf16   2MB
  u16* ow_bf  = uvqk_t + (size_t)EDIM * DIM;        // [512][512]  bf16   0.5MB
  u16* xn     = ow_bf + (size_t)DIM * DIM;          // [8192][512] bf16   8MB
  u16* proj   = xn + (size_t)BNROWS * DIM;          // [8192][2048] bf16  32MB
  float* attn = (float*)(proj + (size_t)BNROWS * EDIM); // [8192][512] f32 16MB
  u16* o_in   = (u16*)(attn + (size_t)BNROWS * DIM);    // [8192][512] bf16 8MB
  u16* vt     = o_in + (size_t)BNROWS * DIM;            // [32][64][2048] bf16 8MB

  k_cast_uvqk<<<dim3(64, 16), 256, 0, stream>>>(uvqk, uvqk_t);
  k_cast_ow<<<dim3(1024), 256, 0, stream>>>(o_w, ow_bf);
  k_ln1<<<dim3(2048), 256, 0, stream>>>(x, xn);
  k_gemm1<<<dim3(1024), 256, 0, stream>>>(xn, uvqk_t, proj, vt);
  k_attn<<<dim3(1024), 256, 0, stream>>>(proj, vt, attn);
  k_ln2<<<dim3(2048), 256, 0, stream>>>(attn, proj, o_in);
  k_gemm2<<<dim3(1024), 256, 0, stream>>>(o_in, ow_bf, o_b, x, out);
}

// Round 9
// 150.142 us; speedup vs baseline: 2.3585x; 1.0023x over previous
//
#include <hip/hip_runtime.h>
#include <cstdint>

#define NTOK 2048
#define DIM 512
#define EDIM 2048
#define BATCH 4
#define HEADS 8
#define BNROWS 8192   /* B*N */
#define INV_N (1.0f/2048.0f)

typedef unsigned short u16;
typedef __bf16 bf16x8 __attribute__((ext_vector_type(8)));
typedef u16   u16x8  __attribute__((ext_vector_type(8)));
typedef u16   u16x4  __attribute__((ext_vector_type(4)));
typedef float f32x4  __attribute__((ext_vector_type(4)));

__device__ __forceinline__ u16 f2bf(float f) {
  union { float f; uint32_t u; } v; v.f = f;
  uint32_t r = v.u + 0x7FFFu + ((v.u >> 16) & 1u);   // RNE
  return (u16)(r >> 16);
}
__device__ __forceinline__ u16 f2bfc(float f) {     // compiler cast (packs to cvt_pk)
  return __builtin_bit_cast(u16, (__bf16)f);
}
__device__ __forceinline__ float bf2f(u16 b) {
  union { uint32_t u; float f; } v; v.u = ((uint32_t)b) << 16;
  return v.f;
}
__device__ __forceinline__ bf16x8 ldb(const u16* p) {
  u16x8 r = *(const u16x8*)p;
  return __builtin_bit_cast(bf16x8, r);
}
#define MFMA16(a,b,c) __builtin_amdgcn_mfma_f32_16x16x32_bf16((a),(b),(c),0,0,0)

// precise silu — attn feeds LayerNorm (rsqrt(var) amplifies perturbations);
// v_rcp variant measurably pushed absmax 0.031 -> 0.125 (round 6). Keep exact.
__device__ __forceinline__ float silu_f(float s) {
  return s / (1.0f + __expf(-s));
}

// async global->LDS, 16B per lane; lds base must be wave-uniform
__device__ __forceinline__ void gload16(const u16* g, u16* lds) {
  __builtin_amdgcn_global_load_lds(
      (const __attribute__((address_space(1))) void*)g,
      (__attribute__((address_space(3))) void*)lds, 16, 0, 0);
}

// ---------------- cast / transpose weights ----------------
__global__ __launch_bounds__(256) void k_cast_uvqk(const float* __restrict__ in,
                                                   u16* __restrict__ out) {
  __shared__ float tile[32][33];
  int tx = threadIdx.x & 31, ty = threadIdx.x >> 5;
  int j0 = blockIdx.x * 32;
  int k0 = blockIdx.y * 32;
#pragma unroll
  for (int r = ty; r < 32; r += 8)
    tile[r][tx] = in[(size_t)(k0 + r) * EDIM + j0 + tx];
  __syncthreads();
#pragma unroll
  for (int r = ty; r < 32; r += 8)
    out[(size_t)(j0 + r) * DIM + k0 + tx] = f2bf(tile[tx][r]);
}

__global__ __launch_bounds__(256) void k_cast_ow(const float* __restrict__ in,
                                                 u16* __restrict__ out) {
  int i = blockIdx.x * 256 + threadIdx.x;
  out[i] = f2bf(in[i]);
}

// ---------------- LayerNorm(x) -> bf16 ----------------
__global__ __launch_bounds__(256) void k_ln1(const float* __restrict__ x,
                                             u16* __restrict__ xn) {
  int lane = threadIdx.x & 63, wid = threadIdx.x >> 6;
  size_t row = (size_t)blockIdx.x * 4 + wid;
  const float* xr = x + row * DIM;
  float4 a = ((const float4*)xr)[lane * 2];
  float4 b = ((const float4*)xr)[lane * 2 + 1];
  float s = a.x + a.y + a.z + a.w + b.x + b.y + b.z + b.w;
#pragma unroll
  for (int o = 32; o; o >>= 1) s += __shfl_xor(s, o);
  float mu = s * (1.0f / DIM);
  float d[8] = {a.x - mu, a.y - mu, a.z - mu, a.w - mu,
                b.x - mu, b.y - mu, b.z - mu, b.w - mu};
  float v = 0.f;
#pragma unroll
  for (int j = 0; j < 8; ++j) v += d[j] * d[j];
#pragma unroll
  for (int o = 32; o; o >>= 1) v += __shfl_xor(v, o);
  float rs = rsqrtf(v * (1.0f / DIM) + 1e-6f);
  u16x8 o8;
#pragma unroll
  for (int j = 0; j < 8; ++j) o8[j] = f2bf(d[j] * rs);
  *(u16x8*)(xn + row * DIM + lane * 8) = o8;
}

// ---------------- GEMM1: proj = silu(xn @ uvqk), fused vt write ----------------
// XCD-chunked 1D grid: each XCD owns 8 row-panels x 16 col-blocks
// (A 1MB + B 2MB < 4MB L2). For v-slice col-blocks (cols 512..1024) the
// epilogue also emits vt[bh][e][n] (bit-identical bf16, 1 b64 store per frag).
__global__ __launch_bounds__(256) void k_gemm1(const u16* __restrict__ A,
                                               const u16* __restrict__ Bt,
                                               u16* __restrict__ P,
                                               u16* __restrict__ vt) {
  __shared__ u16 As[128 * 64];
  __shared__ u16 Bs[128 * 64];
  int tid = threadIdx.x, lane = tid & 63, wid = tid >> 6;
  int lm = lane & 15, lg = lane >> 4;
  int wr = wid >> 1, wc = wid & 1;

  int bid = blockIdx.x;                 // 0..1023
  int xcd = bid & 7, idx = bid >> 3;
  int orig = xcd * 128 + idx;           // 128 contiguous work-items per XCD
  int r0 = (orig >> 4) * 128;           // row-panel (8 per XCD)
  int c0 = (orig & 15) * 128;           // col-block

  int srow = wid * 8 + (lane >> 3);
  int scol = (lane & 7) * 8;

  f32x4 acc[4][4];
  f32x4 z = {0.f, 0.f, 0.f, 0.f};
#pragma unroll
  for (int mt = 0; mt < 4; ++mt)
#pragma unroll
    for (int nt = 0; nt < 4; ++nt) acc[mt][nt] = z;

  for (int ks = 0; ks < DIM / 64; ++ks) {
#pragma unroll
    for (int it = 0; it < 4; ++it) {
      gload16(A + (size_t)(r0 + it * 32 + srow) * DIM + ks * 64 + scol,
              As + it * 2048 + wid * 512);
      gload16(Bt + (size_t)(c0 + it * 32 + srow) * DIM + ks * 64 + scol,
              Bs + it * 2048 + wid * 512);
    }
    __syncthreads();

#pragma unroll
    for (int kk = 0; kk < 2; ++kk) {
      bf16x8 am[4], bn[4];
#pragma unroll
      for (int mt = 0; mt < 4; ++mt)
        am[mt] = ldb(&As[(wr * 64 + mt * 16 + lm) * 64 + kk * 32 + lg * 8]);
#pragma unroll
      for (int nt = 0; nt < 4; ++nt)
        bn[nt] = ldb(&Bs[(wc * 64 + nt * 16 + lm) * 64 + kk * 32 + lg * 8]);
#pragma unroll
      for (int mt = 0; mt < 4; ++mt)
#pragma unroll
        for (int nt = 0; nt < 4; ++nt)
          acc[mt][nt] = MFMA16(am[mt], bn[nt], acc[mt][nt]);
    }
    __syncthreads();
  }

  bool isv = (c0 >= 512) && (c0 < 1024);
  int btc = r0 >> 11;                   // batch index
  int nbw = (r0 & 2047) + wr * 64;      // n base for this wave
  int hv  = ((c0 - 512) >> 6) + wc;     // head (valid when isv)

#pragma unroll
  for (int mt = 0; mt < 4; ++mt)
#pragma unroll
    for (int nt = 0; nt < 4; ++nt) {
      u16 pv[4];
#pragma unroll
      for (int i = 0; i < 4; ++i) {
        size_t row = r0 + wr * 64 + mt * 16 + lg * 4 + i;
        int col = c0 + wc * 64 + nt * 16 + lm;
        pv[i] = f2bf(silu_f(acc[mt][nt][i]));
        P[row * EDIM + col] = pv[i];
      }
      if (isv) {
        int e = nt * 16 + lm;
        int n = nbw + mt * 16 + lg * 4;
        u16x4 pk = {pv[0], pv[1], pv[2], pv[3]};
        *(u16x4*)(vt + ((size_t)(btc * 8 + hv) * 64 + e) * NTOK + n) = pk;
      }
    }
}

// ---------------- HSTU attention v5b ----------------
// 1024 blocks: one 64-row q-tile each, LPT (descending qtile) + XCD-chunked.
// 40KB LDS/block -> 4 blocks/CU. Swapped QK^T (S^T in acc), swizzled p_lds,
// double-buffered K/V^T staging. silu kept PRECISE (LN2 amplifies).
__global__ __launch_bounds__(256) void k_attn(const u16* __restrict__ proj,
                                              const u16* __restrict__ vt,
                                              float* __restrict__ attn) {
  __shared__ u16 kv0[8192];                 // K[64][64] | V^T[64][64]  16KB
  __shared__ u16 kv1[8192];                 // 16KB
  __shared__ u16 p_lds[4][16][64];          // per-wave P[q 16][m 64], XOR-swizzled, 8KB
  int tid = threadIdx.x, lane = tid & 63, w = tid >> 6;
  int lm = lane & 15, lg = lane >> 4;

  // XCD-chunked remap: 4 heads per XCD (2MB K+V^T in its L2); LPT within XCD.
  int bid = blockIdx.x;                     // 0..1023
  int xcd = bid & 7, idx = bid >> 3;        // idx 0..127
  int qtile = 31 - (idx >> 2);              // descending work (LPT)
  int bh = (xcd << 2) + (idx & 3);          // 0..31
  int b = bh >> 3, h = bh & 7;
  int n0 = qtile * 64;
  int nrow = n0 + w * 16;                   // wave's first q row
  int nlm = nrow + lm;                      // this lane's q (column of S^T)

  const u16* pb = proj + (size_t)b * NTOK * EDIM;
  const u16* kb = pb + 1536 + h * 64;
  const u16* vb = vt + (size_t)bh * 64 * NTOK;

  f32x4 z = {0.f, 0.f, 0.f, 0.f};

  // staging: lane l covers LDS row base+(l>>3), phys 16B slot (l&7);
  // source col pre-swizzled so read with col^((row&7)<<3) is linear data.
  int sr = lane >> 3;
  int sc = ((lane & 7) ^ sr) * 8;           // u16 units
  const u16* ks0 = kb + (size_t)(w * 16 + sr) * EDIM + sc;
  const u16* ks1 = kb + (size_t)(w * 16 + 8 + sr) * EDIM + sc;
  const u16* vs0 = vb + (size_t)(w * 16 + sr) * NTOK + sc;
  const u16* vs1 = vb + (size_t)(w * 16 + 8 + sr) * NTOK + sc;

  const u16* qrow = pb + (size_t)nlm * EDIM + 1024 + h * 64 + lg * 8;
  bf16x8 qf0 = ldb(qrow), qf1 = ldb(qrow + 32);

  f32x4 acc[4];
#pragma unroll
  for (int et = 0; et < 4; ++et) acc[et] = z;

  int psw = (lm & 7) << 3;                  // p_lds XOR swizzle for this lane

  // prologue: stage tile 0 -> kv0
  gload16(ks0, kv0 + (w * 16) * 64);
  gload16(ks1, kv0 + (w * 16 + 8) * 64);
  gload16(vs0, kv0 + 4096 + (w * 16) * 64);
  gload16(vs1, kv0 + 4096 + (w * 16 + 8) * 64);
  asm volatile("s_waitcnt vmcnt(0)" ::: "memory");
  __builtin_amdgcn_s_barrier();

  int ntl = qtile + 1;
  for (int t = 0; t < ntl; ++t) {
    const u16* kt = (t & 1) ? kv1 : kv0;
    const u16* vl = kt + 4096;
    if (t + 1 < ntl) {                      // prefetch next tile
      u16* kd = ((t + 1) & 1) ? kv1 : kv0;
      size_t ko = (size_t)(t + 1) * 64 * EDIM;
      size_t vo = (size_t)(t + 1) * 64;
      gload16(ks0 + ko, kd + (w * 16) * 64);
      gload16(ks1 + ko, kd + (w * 16 + 8) * 64);
      gload16(vs0 + vo, kd + 4096 + (w * 16) * 64);
      gload16(vs1 + vo, kd + 4096 + (w * 16 + 8) * 64);
    }
    // ---- QK^T swapped: S^T[m][q]; K as A-frag (same lane map as B-frag)
    bf16x8 kf[4][2];
#pragma unroll
    for (int mb = 0; mb < 4; ++mb)
#pragma unroll
      for (int kk = 0; kk < 2; ++kk)
        kf[mb][kk] = ldb(&kt[(mb * 16 + lm) * 64 +
                             ((kk * 32 + lg * 8) ^ ((lm & 7) << 3))]);
    if (t == qtile) {                       // diagonal tile: masked (wave-uniform)
#pragma unroll
      for (int mb = 0; mb < 4; ++mb) {
        f32x4 s = MFMA16(kf[mb][0], qf0, z);
        s = MFMA16(kf[mb][1], qf1, s);
        int m = t * 64 + mb * 16 + lg * 4;
        u16x4 pk;
#pragma unroll
        for (int i = 0; i < 4; ++i)
          pk[i] = (m + i <= nlm) ? f2bfc(silu_f(s[i])) : (u16)0;
        *(u16x4*)&p_lds[w][lm][(mb * 16 + lg * 4) ^ psw] = pk;
      }
    } else {                                // full tile: no mask
#pragma unroll
      for (int mb = 0; mb < 4; ++mb) {
        f32x4 s = MFMA16(kf[mb][0], qf0, z);
        s = MFMA16(kf[mb][1], qf1, s);
        u16x4 pk;
#pragma unroll
        for (int i = 0; i < 4; ++i) pk[i] = f2bfc(silu_f(s[i]));
        *(u16x4*)&p_lds[w][lm][(mb * 16 + lg * 4) ^ psw] = pk;
      }
    }
    // ---- PV: A = P (rows q, k=m), B = V^T frag
    bf16x8 vf[2][4];
#pragma unroll
    for (int kk = 0; kk < 2; ++kk)
#pragma unroll
      for (int et = 0; et < 4; ++et)
        vf[kk][et] = ldb(&vl[(et * 16 + lm) * 64 +
                             ((kk * 32 + lg * 8) ^ ((lm & 7) << 3))]);
    bf16x8 pf0 = ldb(&p_lds[w][lm][(lg * 8) ^ psw]);
    bf16x8 pf1 = ldb(&p_lds[w][lm][(32 + lg * 8) ^ psw]);
#pragma unroll
    for (int et = 0; et < 4; ++et) {
      acc[et] = MFMA16(pf0, vf[0][et], acc[et]);
      acc[et] = MFMA16(pf1, vf[1][et], acc[et]);
    }
    asm volatile("s_waitcnt vmcnt(0)" ::: "memory");
    __builtin_amdgcn_s_barrier();
  }

#pragma unroll
  for (int et = 0; et < 4; ++et)
#pragma unroll
    for (int i = 0; i < 4; ++i)
      attn[((size_t)b * NTOK + nrow + lg * 4 + i) * DIM +
           h * 64 + et * 16 + lm] = acc[et][i] * INV_N;
}

// ---------------- LN(attn) * u -> bf16 ----------------
__global__ __launch_bounds__(256) void k_ln2(const float* __restrict__ attn,
                                             const u16* __restrict__ proj,
                                             u16* __restrict__ o_in) {
  int lane = threadIdx.x & 63, wid = threadIdx.x >> 6;
  size_t row = (size_t)blockIdx.x * 4 + wid;
  const float* ar = attn + row * DIM;
  float4 a = ((const float4*)ar)[lane * 2];
  float4 b = ((const float4*)ar)[lane * 2 + 1];
  float s = a.x + a.y + a.z + a.w + b.x + b.y + b.z + b.w;
#pragma unroll
  for (int o = 32; o; o >>= 1) s += __shfl_xor(s, o);
  float mu = s * (1.0f / DIM);
  float d[8] = {a.x - mu, a.y - mu, a.z - mu, a.w - mu,
                b.x - mu, b.y - mu, b.z - mu, b.w - mu};
  float v = 0.f;
#pragma unroll
  for (int j = 0; j < 8; ++j) v += d[j] * d[j];
#pragma unroll
  for (int o = 32; o; o >>= 1) v += __shfl_xor(v, o);
  float rs = rsqrtf(v * (1.0f / DIM) + 1e-6f);
  u16x8 u8 = *(const u16x8*)(proj + row * EDIM + lane * 8);
  u16x8 o8;
#pragma unroll
  for (int j = 0; j < 8; ++j) o8[j] = f2bf(bf2f(u8[j]) * (d[j] * rs));
  *(u16x8*)(o_in + row * DIM + lane * 8) = o8;
}

// ---------------- GEMM2: out = o_in @ o_w^T + o_b + x ----------------
// XCD-chunked 1D grid: 16 row-panels x 8 col-blocks per XCD (A-panel L2-local).
__global__ __launch_bounds__(256) void k_gemm2(const u16* __restrict__ A,
                                               const u16* __restrict__ Bw,
                                               const float* __restrict__ o_b,
                                               const float* __restrict__ x,
                                               float* __restrict__ out) {
  int lane = threadIdx.x & 63, wid = threadIdx.x >> 6;
  int lm = lane & 15, lg = lane >> 4;

  int bid = blockIdx.x;                 // 0..1023
  int xcd = bid & 7, idx = bid >> 3;
  int orig = xcd * 128 + idx;
  int r0 = (orig >> 3) * 64 + wid * 16;
  int c0 = (orig & 7) * 64;

  const u16* ap = A + (size_t)(r0 + lm) * DIM + lg * 8;
  const u16* bp = Bw + (size_t)(c0 + lm) * DIM + lg * 8;
  f32x4 acc[4];
  f32x4 z = {0.f, 0.f, 0.f, 0.f};
#pragma unroll
  for (int jt = 0; jt < 4; ++jt) acc[jt] = z;
#pragma unroll 4
  for (int k0 = 0; k0 < DIM; k0 += 32) {
    bf16x8 af = ldb(ap + k0);
#pragma unroll
    for (int jt = 0; jt < 4; ++jt)
      acc[jt] = MFMA16(af, ldb(bp + (size_t)jt * 16 * DIM + k0), acc[jt]);
  }
#pragma unroll
  for (int jt = 0; jt < 4; ++jt)
#pragma unroll
    for (int i = 0; i < 4; ++i) {
      size_t row = r0 + lg * 4 + i;
      int col = c0 + jt * 16 + lm;
      out[row * DIM + col] = acc[jt][i] + o_b[col] + x[row * DIM + col];
    }
}

extern "C" void kernel_launch(void* const* d_in, const int* in_sizes, int n_in,
                              void* d_out, int out_size, void* d_ws, size_t ws_size,
                              hipStream_t stream) {
  const float* x    = (const float*)d_in[0];
  // d_in[1] = invalid_attn_mask: structurally causal tril; applied as predicate.
  const float* uvqk = (const float*)d_in[2];
  const float* o_w  = (const float*)d_in[3];
  const float* o_b  = (const float*)d_in[4];
  float* out = (float*)d_out;

  u16* uvqk_t = (u16*)d_ws;                         // [2048][512] bf16   2MB
  u16* ow_bf  = uvqk_t + (size_t)EDIM * DIM;        // [512][512]  bf16   0.5MB
  u16* xn     = ow_bf + (size_t)DIM * DIM;          // [8192][512] bf16   8MB
  u16* proj   = xn + (size_t)BNROWS * DIM;          // [8192][2048] bf16  32MB
  float* attn = (float*)(proj + (size_t)BNROWS * EDIM); // [8192][512] f32 16MB
  u16* o_in   = (u16*)(attn + (size_t)BNROWS * DIM);    // [8192][512] bf16 8MB
  u16* vt     = o_in + (size_t)BNROWS * DIM;            // [32][64][2048] bf16 8MB

  k_cast_uvqk<<<dim3(64, 16), 256, 0, stream>>>(uvqk, uvqk_t);
  k_cast_ow<<<dim3(1024), 256, 0, stream>>>(o_w, ow_bf);
  k_ln1<<<dim3(2048), 256, 0, stream>>>(x, xn);
  k_gemm1<<<dim3(1024), 256, 0, stream>>>(xn, uvqk_t, proj, vt);
  k_attn<<<dim3(1024), 256, 0, stream>>>(proj, vt, attn);
  k_ln2<<<dim3(2048), 256, 0, stream>>>(attn, proj, o_in);
  k_gemm2<<<dim3(1024), 256, 0, stream>>>(o_in, ow_bf, o_b, x, out);
}

// Round 10
// 112.806 us; speedup vs baseline: 3.1390x; 1.3310x over previous
//
#include <hip/hip_runtime.h>
#include <cstdint>

#define NTOK 2048
#define DIM 512
#define EDIM 2048
#define BATCH 4
#define HEADS 8
#define BNROWS 8192   /* B*N */
#define INV_N (1.0f/2048.0f)

typedef unsigned short u16;
typedef __bf16 bf16x8 __attribute__((ext_vector_type(8)));
typedef u16   u16x8  __attribute__((ext_vector_type(8)));
typedef u16   u16x4  __attribute__((ext_vector_type(4)));
typedef float f32x4  __attribute__((ext_vector_type(4)));

__device__ __forceinline__ u16 f2bf(float f) {
  union { float f; uint32_t u; } v; v.f = f;
  uint32_t r = v.u + 0x7FFFu + ((v.u >> 16) & 1u);   // RNE
  return (u16)(r >> 16);
}
__device__ __forceinline__ u16 f2bfc(float f) {     // compiler cast (packs to cvt_pk)
  return __builtin_bit_cast(u16, (__bf16)f);
}
__device__ __forceinline__ float bf2f(u16 b) {
  union { uint32_t u; float f; } v; v.u = ((uint32_t)b) << 16;
  return v.f;
}
__device__ __forceinline__ bf16x8 ldb(const u16* p) {
  u16x8 r = *(const u16x8*)p;
  return __builtin_bit_cast(bf16x8, r);
}
#define MFMA16(a,b,c) __builtin_amdgcn_mfma_f32_16x16x32_bf16((a),(b),(c),0,0,0)

// silu with NR-refined reciprocal: rcp error squared (<2^-24) => numerically
// equivalent to exact division (round 6 showed RAW rcp is NOT acceptable:
// absmax 0.031->0.125; NR refinement removes that bias). Clamp avoids inf*0=NaN.
__device__ __forceinline__ float silu_nr(float s) {
  float e = __expf(-s);
  e = fminf(e, 1.7e38f);
  float d = 1.0f + e;
  float r = __builtin_amdgcn_rcpf(d);
  r = r * fmaf(-d, r, 2.0f);
  return s * r;
}

// async global->LDS, 16B per lane; lds base must be wave-uniform
__device__ __forceinline__ void gload16(const u16* g, u16* lds) {
  __builtin_amdgcn_global_load_lds(
      (const __attribute__((address_space(1))) void*)g,
      (__attribute__((address_space(3))) void*)lds, 16, 0, 0);
}

// ---------------- fused prologue: uvqk transpose-cast | ow cast | ln1 ----------------
__global__ __launch_bounds__(256) void k_pre(const float* __restrict__ uvqk,
                                             const float* __restrict__ ow,
                                             const float* __restrict__ x,
                                             u16* __restrict__ uvqk_t,
                                             u16* __restrict__ ow_bf,
                                             u16* __restrict__ xn) {
  __shared__ float tile[32][33];
  int bid = blockIdx.x, tid = threadIdx.x;
  if (bid < 1024) {
    // uvqk: f32 [512][2048] -> bf16 [2048][512]
    int tx = tid & 31, ty = tid >> 5;
    int j0 = (bid & 63) * 32, k0 = (bid >> 6) * 32;
#pragma unroll
    for (int r = ty; r < 32; r += 8)
      tile[r][tx] = uvqk[(size_t)(k0 + r) * EDIM + j0 + tx];
    __syncthreads();
#pragma unroll
    for (int r = ty; r < 32; r += 8)
      uvqk_t[(size_t)(j0 + r) * DIM + k0 + tx] = f2bf(tile[tx][r]);
  } else if (bid < 1280) {
    // ow cast: 512*512 f32 -> bf16
    int i4 = (bid - 1024) * 1024 + tid * 4;
    float4 v = *(const float4*)(ow + i4);
    u16x4 o = {f2bf(v.x), f2bf(v.y), f2bf(v.z), f2bf(v.w)};
    *(u16x4*)(ow_bf + i4) = o;
  } else {
    // ln1: 4 rows per block
    int lane = tid & 63, wid = tid >> 6;
    size_t row = (size_t)(bid - 1280) * 4 + wid;
    const float* xr = x + row * DIM;
    float4 a = ((const float4*)xr)[lane * 2];
    float4 b = ((const float4*)xr)[lane * 2 + 1];
    float s = a.x + a.y + a.z + a.w + b.x + b.y + b.z + b.w;
#pragma unroll
    for (int o = 32; o; o >>= 1) s += __shfl_xor(s, o);
    float mu = s * (1.0f / DIM);
    float d[8] = {a.x - mu, a.y - mu, a.z - mu, a.w - mu,
                  b.x - mu, b.y - mu, b.z - mu, b.w - mu};
    float v = 0.f;
#pragma unroll
    for (int j = 0; j < 8; ++j) v += d[j] * d[j];
#pragma unroll
    for (int o = 32; o; o >>= 1) v += __shfl_xor(v, o);
    float rs = rsqrtf(v * (1.0f / DIM) + 1e-6f);
    u16x8 o8;
#pragma unroll
    for (int j = 0; j < 8; ++j) o8[j] = f2bf(d[j] * rs);
    *(u16x8*)(xn + row * DIM + lane * 8) = o8;
  }
}

// ---------------- GEMM1: proj = silu(xn @ uvqk), fused vt write ----------------
// XCD-chunked 1D grid: each XCD owns 8 row-panels x 16 col-blocks.
__global__ __launch_bounds__(256) void k_gemm1(const u16* __restrict__ A,
                                               const u16* __restrict__ Bt,
                                               u16* __restrict__ P,
                                               u16* __restrict__ vt) {
  __shared__ u16 As[128 * 64];
  __shared__ u16 Bs[128 * 64];
  int tid = threadIdx.x, lane = tid & 63, wid = tid >> 6;
  int lm = lane & 15, lg = lane >> 4;
  int wr = wid >> 1, wc = wid & 1;

  int bid = blockIdx.x;                 // 0..1023
  int xcd = bid & 7, idx = bid >> 3;
  int orig = xcd * 128 + idx;           // 128 contiguous work-items per XCD
  int r0 = (orig >> 4) * 128;           // row-panel (8 per XCD)
  int c0 = (orig & 15) * 128;           // col-block

  int srow = wid * 8 + (lane >> 3);
  int scol = (lane & 7) * 8;

  f32x4 acc[4][4];
  f32x4 z = {0.f, 0.f, 0.f, 0.f};
#pragma unroll
  for (int mt = 0; mt < 4; ++mt)
#pragma unroll
    for (int nt = 0; nt < 4; ++nt) acc[mt][nt] = z;

  for (int ks = 0; ks < DIM / 64; ++ks) {
#pragma unroll
    for (int it = 0; it < 4; ++it) {
      gload16(A + (size_t)(r0 + it * 32 + srow) * DIM + ks * 64 + scol,
              As + it * 2048 + wid * 512);
      gload16(Bt + (size_t)(c0 + it * 32 + srow) * DIM + ks * 64 + scol,
              Bs + it * 2048 + wid * 512);
    }
    __syncthreads();

#pragma unroll
    for (int kk = 0; kk < 2; ++kk) {
      bf16x8 am[4], bn[4];
#pragma unroll
      for (int mt = 0; mt < 4; ++mt)
        am[mt] = ldb(&As[(wr * 64 + mt * 16 + lm) * 64 + kk * 32 + lg * 8]);
#pragma unroll
      for (int nt = 0; nt < 4; ++nt)
        bn[nt] = ldb(&Bs[(wc * 64 + nt * 16 + lm) * 64 + kk * 32 + lg * 8]);
#pragma unroll
      for (int mt = 0; mt < 4; ++mt)
#pragma unroll
        for (int nt = 0; nt < 4; ++nt)
          acc[mt][nt] = MFMA16(am[mt], bn[nt], acc[mt][nt]);
    }
    __syncthreads();
  }

  bool isv = (c0 >= 512) && (c0 < 1024);
  int btc = r0 >> 11;                   // batch index
  int nbw = (r0 & 2047) + wr * 64;      // n base for this wave
  int hv  = ((c0 - 512) >> 6) + wc;     // head (valid when isv)

#pragma unroll
  for (int mt = 0; mt < 4; ++mt)
#pragma unroll
    for (int nt = 0; nt < 4; ++nt) {
      u16 pv[4];
#pragma unroll
      for (int i = 0; i < 4; ++i) {
        size_t row = r0 + wr * 64 + mt * 16 + lg * 4 + i;
        int col = c0 + wc * 64 + nt * 16 + lm;
        pv[i] = f2bf(silu_nr(acc[mt][nt][i]));
        P[row * EDIM + col] = pv[i];
      }
      if (isv) {
        int e = nt * 16 + lm;
        int n = nbw + mt * 16 + lg * 4;
        u16x4 pk = {pv[0], pv[1], pv[2], pv[3]};
        *(u16x4*)(vt + ((size_t)(btc * 8 + hv) * 64 + e) * NTOK + n) = pk;
      }
    }
}

// ---------------- HSTU attention v6 (v5b + NR silu) ----------------
__global__ __launch_bounds__(256) void k_attn(const u16* __restrict__ proj,
                                              const u16* __restrict__ vt,
                                              float* __restrict__ attn) {
  __shared__ u16 kv0[8192];                 // K[64][64] | V^T[64][64]  16KB
  __shared__ u16 kv1[8192];                 // 16KB
  __shared__ u16 p_lds[4][16][64];          // per-wave P[q 16][m 64], XOR-swizzled, 8KB
  int tid = threadIdx.x, lane = tid & 63, w = tid >> 6;
  int lm = lane & 15, lg = lane >> 4;

  int bid = blockIdx.x;                     // 0..1023
  int xcd = bid & 7, idx = bid >> 3;        // idx 0..127
  int qtile = 31 - (idx >> 2);              // descending work (LPT)
  int bh = (xcd << 2) + (idx & 3);          // 0..31
  int b = bh >> 3, h = bh & 7;
  int n0 = qtile * 64;
  int nrow = n0 + w * 16;                   // wave's first q row
  int nlm = nrow + lm;                      // this lane's q (column of S^T)

  const u16* pb = proj + (size_t)b * NTOK * EDIM;
  const u16* kb = pb + 1536 + h * 64;
  const u16* vb = vt + (size_t)bh * 64 * NTOK;

  f32x4 z = {0.f, 0.f, 0.f, 0.f};

  int sr = lane >> 3;
  int sc = ((lane & 7) ^ sr) * 8;           // u16 units (pre-swizzled source)
  const u16* ks0 = kb + (size_t)(w * 16 + sr) * EDIM + sc;
  const u16* ks1 = kb + (size_t)(w * 16 + 8 + sr) * EDIM + sc;
  const u16* vs0 = vb + (size_t)(w * 16 + sr) * NTOK + sc;
  const u16* vs1 = vb + (size_t)(w * 16 + 8 + sr) * NTOK + sc;

  const u16* qrow = pb + (size_t)nlm * EDIM + 1024 + h * 64 + lg * 8;
  bf16x8 qf0 = ldb(qrow), qf1 = ldb(qrow + 32);

  f32x4 acc[4];
#pragma unroll
  for (int et = 0; et < 4; ++et) acc[et] = z;

  int psw = (lm & 7) << 3;                  // p_lds XOR swizzle for this lane

  gload16(ks0, kv0 + (w * 16) * 64);
  gload16(ks1, kv0 + (w * 16 + 8) * 64);
  gload16(vs0, kv0 + 4096 + (w * 16) * 64);
  gload16(vs1, kv0 + 4096 + (w * 16 + 8) * 64);
  asm volatile("s_waitcnt vmcnt(0)" ::: "memory");
  __builtin_amdgcn_s_barrier();

  int ntl = qtile + 1;
  for (int t = 0; t < ntl; ++t) {
    const u16* kt = (t & 1) ? kv1 : kv0;
    const u16* vl = kt + 4096;
    if (t + 1 < ntl) {                      // prefetch next tile
      u16* kd = ((t + 1) & 1) ? kv1 : kv0;
      size_t ko = (size_t)(t + 1) * 64 * EDIM;
      size_t vo = (size_t)(t + 1) * 64;
      gload16(ks0 + ko, kd + (w * 16) * 64);
      gload16(ks1 + ko, kd + (w * 16 + 8) * 64);
      gload16(vs0 + vo, kd + 4096 + (w * 16) * 64);
      gload16(vs1 + vo, kd + 4096 + (w * 16 + 8) * 64);
    }
    bf16x8 kf[4][2];
#pragma unroll
    for (int mb = 0; mb < 4; ++mb)
#pragma unroll
      for (int kk = 0; kk < 2; ++kk)
        kf[mb][kk] = ldb(&kt[(mb * 16 + lm) * 64 +
                             ((kk * 32 + lg * 8) ^ ((lm & 7) << 3))]);
    if (t == qtile) {                       // diagonal tile: masked
#pragma unroll
      for (int mb = 0; mb < 4; ++mb) {
        f32x4 s = MFMA16(kf[mb][0], qf0, z);
        s = MFMA16(kf[mb][1], qf1, s);
        int m = t * 64 + mb * 16 + lg * 4;
        u16x4 pk;
#pragma unroll
        for (int i = 0; i < 4; ++i)
          pk[i] = (m + i <= nlm) ? f2bfc(silu_nr(s[i])) : (u16)0;
        *(u16x4*)&p_lds[w][lm][(mb * 16 + lg * 4) ^ psw] = pk;
      }
    } else {                                // full tile
#pragma unroll
      for (int mb = 0; mb < 4; ++mb) {
        f32x4 s = MFMA16(kf[mb][0], qf0, z);
        s = MFMA16(kf[mb][1], qf1, s);
        u16x4 pk;
#pragma unroll
        for (int i = 0; i < 4; ++i) pk[i] = f2bfc(silu_nr(s[i]));
        *(u16x4*)&p_lds[w][lm][(mb * 16 + lg * 4) ^ psw] = pk;
      }
    }
    bf16x8 vf[2][4];
#pragma unroll
    for (int kk = 0; kk < 2; ++kk)
#pragma unroll
      for (int et = 0; et < 4; ++et)
        vf[kk][et] = ldb(&vl[(et * 16 + lm) * 64 +
                             ((kk * 32 + lg * 8) ^ ((lm & 7) << 3))]);
    bf16x8 pf0 = ldb(&p_lds[w][lm][(lg * 8) ^ psw]);
    bf16x8 pf1 = ldb(&p_lds[w][lm][(32 + lg * 8) ^ psw]);
#pragma unroll
    for (int et = 0; et < 4; ++et) {
      acc[et] = MFMA16(pf0, vf[0][et], acc[et]);
      acc[et] = MFMA16(pf1, vf[1][et], acc[et]);
    }
    asm volatile("s_waitcnt vmcnt(0)" ::: "memory");
    __builtin_amdgcn_s_barrier();
  }

#pragma unroll
  for (int et = 0; et < 4; ++et)
#pragma unroll
    for (int i = 0; i < 4; ++i)
      attn[((size_t)b * NTOK + nrow + lg * 4 + i) * DIM +
           h * 64 + et * 16 + lm] = acc[et][i] * INV_N;
}

// ---------------- fused LN2 + GEMM2: out = (LN(attn)*u) @ o_w^T + o_b + x ----------------
// 256 blocks (1/CU), 32 rows x full 512 cols each, XCD-chunked rows.
// Phase 1: LN per row into 32KB XOR-swizzled LDS (bit-identical math to old k_ln2).
// Phase 2: MFMA from LDS A vs L2-resident o_w.
__global__ __launch_bounds__(256) void k_gemm2f(const float* __restrict__ attn,
                                                const u16* __restrict__ proj,
                                                const u16* __restrict__ Bw,
                                                const float* __restrict__ o_b,
                                                const float* __restrict__ x,
                                                float* __restrict__ out) {
  __shared__ u16 os[32 * 512];              // LN(attn)*u, bf16, swizzled cols
  int tid = threadIdx.x, lane = tid & 63, w = tid >> 6;
  int lm = lane & 15, lg = lane >> 4;

  int bid = blockIdx.x;                     // 0..255
  int xcd = bid & 7, idx = bid >> 3;        // 32 blocks per XCD
  int r0 = (xcd * 32 + idx) * 32;           // 1024-row panel per XCD

  // ---- Phase 1: LN rows w*8 .. w*8+7 ----
#pragma unroll
  for (int rr = 0; rr < 8; ++rr) {
    int r = w * 8 + rr;
    const float* ar = attn + (size_t)(r0 + r) * DIM;
    float4 a = ((const float4*)ar)[lane * 2];
    float4 b = ((const float4*)ar)[lane * 2 + 1];
    float s = a.x + a.y + a.z + a.w + b.x + b.y + b.z + b.w;
#pragma unroll
    for (int o = 32; o; o >>= 1) s += __shfl_xor(s, o);
    float mu = s * (1.0f / DIM);
    float d[8] = {a.x - mu, a.y - mu, a.z - mu, a.w - mu,
                  b.x - mu, b.y - mu, b.z - mu, b.w - mu};
    float v = 0.f;
#pragma unroll
    for (int j = 0; j < 8; ++j) v += d[j] * d[j];
#pragma unroll
    for (int o = 32; o; o >>= 1) v += __shfl_xor(v, o);
    float rs = rsqrtf(v * (1.0f / DIM) + 1e-6f);
    u16x8 u8 = *(const u16x8*)(proj + (size_t)(r0 + r) * EDIM + lane * 8);
    u16x8 o8;
#pragma unroll
    for (int j = 0; j < 8; ++j) o8[j] = f2bf(bf2f(u8[j]) * (d[j] * rs));
    *(u16x8*)&os[r * 512 + ((lane * 8) ^ ((r & 7) << 3))] = o8;
  }
  __syncthreads();

  // ---- Phase 2: GEMM, wave w covers cols w*128..w*128+127 ----
  int cb = w * 128;
  f32x4 acc[2][8];
  f32x4 z = {0.f, 0.f, 0.f, 0.f};
#pragma unroll
  for (int mt = 0; mt < 2; ++mt)
#pragma unroll
    for (int nt = 0; nt < 8; ++nt) acc[mt][nt] = z;

#pragma unroll 2
  for (int kc = 0; kc < 16; ++kc) {
    bf16x8 af[2];
#pragma unroll
    for (int mt = 0; mt < 2; ++mt)
      af[mt] = ldb(&os[(mt * 16 + lm) * 512 +
                       ((kc * 32 + lg * 8) ^ ((lm & 7) << 3))]);
    bf16x8 bfr[8];
#pragma unroll
    for (int nt = 0; nt < 8; ++nt)
      bfr[nt] = ldb(Bw + (size_t)(cb + nt * 16 + lm) * DIM + kc * 32 + lg * 8);
#pragma unroll
    for (int mt = 0; mt < 2; ++mt)
#pragma unroll
      for (int nt = 0; nt < 8; ++nt)
        acc[mt][nt] = MFMA16(af[mt], bfr[nt], acc[mt][nt]);
  }

#pragma unroll
  for (int mt = 0; mt < 2; ++mt)
#pragma unroll
    for (int nt = 0; nt < 8; ++nt)
#pragma unroll
      for (int i = 0; i < 4; ++i) {
        size_t row = r0 + mt * 16 + lg * 4 + i;
        int col = cb + nt * 16 + lm;
        out[row * DIM + col] = acc[mt][nt][i] + o_b[col] + x[row * DIM + col];
      }
}

extern "C" void kernel_launch(void* const* d_in, const int* in_sizes, int n_in,
                              void* d_out, int out_size, void* d_ws, size_t ws_size,
                              hipStream_t stream) {
  const float* x    = (const float*)d_in[0];
  // d_in[1] = invalid_attn_mask: structurally causal tril; applied as predicate.
  const float* uvqk = (const float*)d_in[2];
  const float* o_w  = (const float*)d_in[3];
  const float* o_b  = (const float*)d_in[4];
  float* out = (float*)d_out;

  u16* uvqk_t = (u16*)d_ws;                         // [2048][512] bf16   2MB
  u16* ow_bf  = uvqk_t + (size_t)EDIM * DIM;        // [512][512]  bf16   0.5MB
  u16* xn     = ow_bf + (size_t)DIM * DIM;          // [8192][512] bf16   8MB
  u16* proj   = xn + (size_t)BNROWS * DIM;          // [8192][2048] bf16  32MB
  float* attn = (float*)(proj + (size_t)BNROWS * EDIM); // [8192][512] f32 16MB
  u16* o_in   = (u16*)(attn + (size_t)BNROWS * DIM);    // (unused now)   8MB
  u16* vt     = o_in + (size_t)BNROWS * DIM;            // [32][64][2048] bf16 8MB

  k_pre<<<dim3(3328), 256, 0, stream>>>(uvqk, o_w, x, uvqk_t, ow_bf, xn);
  k_gemm1<<<dim3(1024), 256, 0, stream>>>(xn, uvqk_t, proj, vt);
  k_attn<<<dim3(1024), 256, 0, stream>>>(proj, vt, attn);
  k_gemm2f<<<dim3(256), 256, 0, stream>>>(attn, proj, ow_bf, o_b, x, out);
}

// Round 11
// 112.599 us; speedup vs baseline: 3.1448x; 1.0018x over previous
//
#include <hip/hip_runtime.h>
#include <cstdint>

#define NTOK 2048
#define DIM 512
#define EDIM 2048
#define BATCH 4
#define HEADS 8
#define BNROWS 8192   /* B*N */
#define INV_N (1.0f/2048.0f)

typedef unsigned short u16;
typedef __bf16 bf16x8 __attribute__((ext_vector_type(8)));
typedef u16   u16x8  __attribute__((ext_vector_type(8)));
typedef u16   u16x4  __attribute__((ext_vector_type(4)));
typedef float f32x4  __attribute__((ext_vector_type(4)));

__device__ __forceinline__ u16 f2bf(float f) {
  union { float f; uint32_t u; } v; v.f = f;
  uint32_t r = v.u + 0x7FFFu + ((v.u >> 16) & 1u);   // RNE
  return (u16)(r >> 16);
}
__device__ __forceinline__ u16 f2bfc(float f) {     // compiler cast (packs to cvt_pk, RNE)
  return __builtin_bit_cast(u16, (__bf16)f);
}
__device__ __forceinline__ float bf2f(u16 b) {
  union { uint32_t u; float f; } v; v.u = ((uint32_t)b) << 16;
  return v.f;
}
__device__ __forceinline__ bf16x8 ldb(const u16* p) {
  u16x8 r = *(const u16x8*)p;
  return __builtin_bit_cast(bf16x8, r);
}
#define MFMA16(a,b,c) __builtin_amdgcn_mfma_f32_16x16x32_bf16((a),(b),(c),0,0,0)

// silu with NR-refined reciprocal: rcp error squared (<2^-24) => numerically
// equivalent to exact division (round 6: RAW rcp is NOT acceptable). Clamp
// avoids inf -> NaN in the NR step.
__device__ __forceinline__ float silu_nr(float s) {
  float e = __expf(-s);
  e = fminf(e, 1.7e38f);
  float d = 1.0f + e;
  float r = __builtin_amdgcn_rcpf(d);
  r = r * fmaf(-d, r, 2.0f);
  return s * r;
}

// async global->LDS, 16B per lane; lds base must be wave-uniform
__device__ __forceinline__ void gload16(const u16* g, u16* lds) {
  __builtin_amdgcn_global_load_lds(
      (const __attribute__((address_space(1))) void*)g,
      (__attribute__((address_space(3))) void*)lds, 16, 0, 0);
}

// ---------------- fused prologue: uvqk transpose-cast | ow cast | ln1 ----------------
__global__ __launch_bounds__(256) void k_pre(const float* __restrict__ uvqk,
                                             const float* __restrict__ ow,
                                             const float* __restrict__ x,
                                             u16* __restrict__ uvqk_t,
                                             u16* __restrict__ ow_bf,
                                             u16* __restrict__ xn) {
  __shared__ float tile[32][33];
  int bid = blockIdx.x, tid = threadIdx.x;
  if (bid < 1024) {
    // uvqk: f32 [512][2048] -> bf16 [2048][512]
    int tx = tid & 31, ty = tid >> 5;
    int j0 = (bid & 63) * 32, k0 = (bid >> 6) * 32;
#pragma unroll
    for (int r = ty; r < 32; r += 8)
      tile[r][tx] = uvqk[(size_t)(k0 + r) * EDIM + j0 + tx];
    __syncthreads();
#pragma unroll
    for (int r = ty; r < 32; r += 8)
      uvqk_t[(size_t)(j0 + r) * DIM + k0 + tx] = f2bfc(tile[tx][r]);
  } else if (bid < 1280) {
    // ow cast: 512*512 f32 -> bf16
    int i4 = (bid - 1024) * 1024 + tid * 4;
    float4 v = *(const float4*)(ow + i4);
    u16x4 o = {f2bfc(v.x), f2bfc(v.y), f2bfc(v.z), f2bfc(v.w)};
    *(u16x4*)(ow_bf + i4) = o;
  } else {
    // ln1: 4 rows per block
    int lane = tid & 63, wid = tid >> 6;
    size_t row = (size_t)(bid - 1280) * 4 + wid;
    const float* xr = x + row * DIM;
    float4 a = ((const float4*)xr)[lane * 2];
    float4 b = ((const float4*)xr)[lane * 2 + 1];
    float s = a.x + a.y + a.z + a.w + b.x + b.y + b.z + b.w;
#pragma unroll
    for (int o = 32; o; o >>= 1) s += __shfl_xor(s, o);
    float mu = s * (1.0f / DIM);
    float d[8] = {a.x - mu, a.y - mu, a.z - mu, a.w - mu,
                  b.x - mu, b.y - mu, b.z - mu, b.w - mu};
    float v = 0.f;
#pragma unroll
    for (int j = 0; j < 8; ++j) v += d[j] * d[j];
#pragma unroll
    for (int o = 32; o; o >>= 1) v += __shfl_xor(v, o);
    float rs = rsqrtf(v * (1.0f / DIM) + 1e-6f);
    u16x8 o8;
#pragma unroll
    for (int j = 0; j < 8; ++j) o8[j] = f2bfc(d[j] * rs);
    *(u16x8*)(xn + row * DIM + lane * 8) = o8;
  }
}

// ---------------- GEMM1: proj = silu(xn @ uvqk), fused vt write ----------------
// XCD-chunked 1D grid: each XCD owns 8 row-panels x 16 col-blocks.
// Epilogue: per-wave LDS-transpose (reusing As/Bs) -> b128 coalesced P stores
// (replaces 64 scalar 2B stores/thread; K=512 makes the epilogue ~1/8 of work).
__global__ __launch_bounds__(256) void k_gemm1(const u16* __restrict__ A,
                                               const u16* __restrict__ Bt,
                                               u16* __restrict__ P,
                                               u16* __restrict__ vt) {
  __shared__ u16 As[128 * 64];
  __shared__ u16 Bs[128 * 64];
  int tid = threadIdx.x, lane = tid & 63, wid = tid >> 6;
  int lm = lane & 15, lg = lane >> 4;
  int wr = wid >> 1, wc = wid & 1;

  int bid = blockIdx.x;                 // 0..1023
  int xcd = bid & 7, idx = bid >> 3;
  int orig = xcd * 128 + idx;           // 128 contiguous work-items per XCD
  int r0 = (orig >> 4) * 128;           // row-panel (8 per XCD)
  int c0 = (orig & 15) * 128;           // col-block

  int srow = wid * 8 + (lane >> 3);
  int scol = (lane & 7) * 8;

  f32x4 acc[4][4];
  f32x4 z = {0.f, 0.f, 0.f, 0.f};
#pragma unroll
  for (int mt = 0; mt < 4; ++mt)
#pragma unroll
    for (int nt = 0; nt < 4; ++nt) acc[mt][nt] = z;

  for (int ks = 0; ks < DIM / 64; ++ks) {
#pragma unroll
    for (int it = 0; it < 4; ++it) {
      gload16(A + (size_t)(r0 + it * 32 + srow) * DIM + ks * 64 + scol,
              As + it * 2048 + wid * 512);
      gload16(Bt + (size_t)(c0 + it * 32 + srow) * DIM + ks * 64 + scol,
              Bs + it * 2048 + wid * 512);
    }
    __syncthreads();

#pragma unroll
    for (int kk = 0; kk < 2; ++kk) {
      bf16x8 am[4], bn[4];
#pragma unroll
      for (int mt = 0; mt < 4; ++mt)
        am[mt] = ldb(&As[(wr * 64 + mt * 16 + lm) * 64 + kk * 32 + lg * 8]);
#pragma unroll
      for (int nt = 0; nt < 4; ++nt)
        bn[nt] = ldb(&Bs[(wc * 64 + nt * 16 + lm) * 64 + kk * 32 + lg * 8]);
#pragma unroll
      for (int mt = 0; mt < 4; ++mt)
#pragma unroll
        for (int nt = 0; nt < 4; ++nt)
          acc[mt][nt] = MFMA16(am[mt], bn[nt], acc[mt][nt]);
    }
    __syncthreads();
  }

  bool isv = (c0 >= 512) && (c0 < 1024);
  int btc = r0 >> 11;                   // batch index
  int nbw = (r0 & 2047) + wr * 64;      // n base for this wave
  int hv  = ((c0 - 512) >> 6) + wc;     // head (valid when isv)

  // per-wave 8KB scratch region (As/Bs dead after last barrier)
  u16* ws = ((wid >> 1) ? Bs : As) + (wid & 1) * 4096;

#pragma unroll
  for (int mt = 0; mt < 4; ++mt)
#pragma unroll
    for (int nt = 0; nt < 4; ++nt) {
      u16 pv[4];
#pragma unroll
      for (int i = 0; i < 4; ++i) {
        pv[i] = f2bfc(silu_nr(acc[mt][nt][i]));
        int row = mt * 16 + lg * 4 + i;            // local row (0..63)
        int col = nt * 16 + lm;                    // local col (0..63)
        ws[row * 64 + (col ^ ((row & 7) << 3))] = pv[i];
      }
      if (isv) {
        int e = nt * 16 + lm;
        int n = nbw + mt * 16 + lg * 4;
        u16x4 pk = {pv[0], pv[1], pv[2], pv[3]};
        *(u16x4*)(vt + ((size_t)(btc * 8 + hv) * 64 + e) * NTOK + n) = pk;
      }
    }

  // read back row-contiguous (same-wave dep; compiler inserts lgkmcnt)
#pragma unroll
  for (int p = 0; p < 8; ++p) {
    int rrow = p * 8 + (lane >> 3);
    int rcol = (lane & 7) * 8;
    u16x8 vv = *(const u16x8*)&ws[rrow * 64 + (rcol ^ ((rrow & 7) << 3))];
    *(u16x8*)(P + (size_t)(r0 + wr * 64 + rrow) * EDIM + c0 + wc * 64 + rcol) = vv;
  }
}

// ---------------- HSTU attention v6 (frozen since round 10) ----------------
__global__ __launch_bounds__(256) void k_attn(const u16* __restrict__ proj,
                                              const u16* __restrict__ vt,
                                              float* __restrict__ attn) {
  __shared__ u16 kv0[8192];                 // K[64][64] | V^T[64][64]  16KB
  __shared__ u16 kv1[8192];                 // 16KB
  __shared__ u16 p_lds[4][16][64];          // per-wave P[q 16][m 64], XOR-swizzled, 8KB
  int tid = threadIdx.x, lane = tid & 63, w = tid >> 6;
  int lm = lane & 15, lg = lane >> 4;

  int bid = blockIdx.x;                     // 0..1023
  int xcd = bid & 7, idx = bid >> 3;        // idx 0..127
  int qtile = 31 - (idx >> 2);              // descending work (LPT)
  int bh = (xcd << 2) + (idx & 3);          // 0..31
  int b = bh >> 3, h = bh & 7;
  int n0 = qtile * 64;
  int nrow = n0 + w * 16;                   // wave's first q row
  int nlm = nrow + lm;                      // this lane's q (column of S^T)

  const u16* pb = proj + (size_t)b * NTOK * EDIM;
  const u16* kb = pb + 1536 + h * 64;
  const u16* vb = vt + (size_t)bh * 64 * NTOK;

  f32x4 z = {0.f, 0.f, 0.f, 0.f};

  int sr = lane >> 3;
  int sc = ((lane & 7) ^ sr) * 8;           // u16 units (pre-swizzled source)
  const u16* ks0 = kb + (size_t)(w * 16 + sr) * EDIM + sc;
  const u16* ks1 = kb + (size_t)(w * 16 + 8 + sr) * EDIM + sc;
  const u16* vs0 = vb + (size_t)(w * 16 + sr) * NTOK + sc;
  const u16* vs1 = vb + (size_t)(w * 16 + 8 + sr) * NTOK + sc;

  const u16* qrow = pb + (size_t)nlm * EDIM + 1024 + h * 64 + lg * 8;
  bf16x8 qf0 = ldb(qrow), qf1 = ldb(qrow + 32);

  f32x4 acc[4];
#pragma unroll
  for (int et = 0; et < 4; ++et) acc[et] = z;

  int psw = (lm & 7) << 3;                  // p_lds XOR swizzle for this lane

  gload16(ks0, kv0 + (w * 16) * 64);
  gload16(ks1, kv0 + (w * 16 + 8) * 64);
  gload16(vs0, kv0 + 4096 + (w * 16) * 64);
  gload16(vs1, kv0 + 4096 + (w * 16 + 8) * 64);
  asm volatile("s_waitcnt vmcnt(0)" ::: "memory");
  __builtin_amdgcn_s_barrier();

  int ntl = qtile + 1;
  for (int t = 0; t < ntl; ++t) {
    const u16* kt = (t & 1) ? kv1 : kv0;
    const u16* vl = kt + 4096;
    if (t + 1 < ntl) {                      // prefetch next tile
      u16* kd = ((t + 1) & 1) ? kv1 : kv0;
      size_t ko = (size_t)(t + 1) * 64 * EDIM;
      size_t vo = (size_t)(t + 1) * 64;
      gload16(ks0 + ko, kd + (w * 16) * 64);
      gload16(ks1 + ko, kd + (w * 16 + 8) * 64);
      gload16(vs0 + vo, kd + 4096 + (w * 16) * 64);
      gload16(vs1 + vo, kd + 4096 + (w * 16 + 8) * 64);
    }
    bf16x8 kf[4][2];
#pragma unroll
    for (int mb = 0; mb < 4; ++mb)
#pragma unroll
      for (int kk = 0; kk < 2; ++kk)
        kf[mb][kk] = ldb(&kt[(mb * 16 + lm) * 64 +
                             ((kk * 32 + lg * 8) ^ ((lm & 7) << 3))]);
    if (t == qtile) {                       // diagonal tile: masked
#pragma unroll
      for (int mb = 0; mb < 4; ++mb) {
        f32x4 s = MFMA16(kf[mb][0], qf0, z);
        s = MFMA16(kf[mb][1], qf1, s);
        int m = t * 64 + mb * 16 + lg * 4;
        u16x4 pk;
#pragma unroll
        for (int i = 0; i < 4; ++i)
          pk[i] = (m + i <= nlm) ? f2bfc(silu_nr(s[i])) : (u16)0;
        *(u16x4*)&p_lds[w][lm][(mb * 16 + lg * 4) ^ psw] = pk;
      }
    } else {                                // full tile
#pragma unroll
      for (int mb = 0; mb < 4; ++mb) {
        f32x4 s = MFMA16(kf[mb][0], qf0, z);
        s = MFMA16(kf[mb][1], qf1, s);
        u16x4 pk;
#pragma unroll
        for (int i = 0; i < 4; ++i) pk[i] = f2bfc(silu_nr(s[i]));
        *(u16x4*)&p_lds[w][lm][(mb * 16 + lg * 4) ^ psw] = pk;
      }
    }
    bf16x8 vf[2][4];
#pragma unroll
    for (int kk = 0; kk < 2; ++kk)
#pragma unroll
      for (int et = 0; et < 4; ++et)
        vf[kk][et] = ldb(&vl[(et * 16 + lm) * 64 +
                             ((kk * 32 + lg * 8) ^ ((lm & 7) << 3))]);
    bf16x8 pf0 = ldb(&p_lds[w][lm][(lg * 8) ^ psw]);
    bf16x8 pf1 = ldb(&p_lds[w][lm][(32 + lg * 8) ^ psw]);
#pragma unroll
    for (int et = 0; et < 4; ++et) {
      acc[et] = MFMA16(pf0, vf[0][et], acc[et]);
      acc[et] = MFMA16(pf1, vf[1][et], acc[et]);
    }
    asm volatile("s_waitcnt vmcnt(0)" ::: "memory");
    __builtin_amdgcn_s_barrier();
  }

#pragma unroll
  for (int et = 0; et < 4; ++et)
#pragma unroll
    for (int i = 0; i < 4; ++i)
      attn[((size_t)b * NTOK + nrow + lg * 4 + i) * DIM +
           h * 64 + et * 16 + lm] = acc[et][i] * INV_N;
}

// ---------------- fused LN2 + GEMM2: out = (LN(attn)*u) @ o_w^T + o_b + x ----------------
__global__ __launch_bounds__(256) void k_gemm2f(const float* __restrict__ attn,
                                                const u16* __restrict__ proj,
                                                const u16* __restrict__ Bw,
                                                const float* __restrict__ o_b,
                                                const float* __restrict__ x,
                                                float* __restrict__ out) {
  __shared__ u16 os[32 * 512];              // LN(attn)*u, bf16, swizzled cols
  int tid = threadIdx.x, lane = tid & 63, w = tid >> 6;
  int lm = lane & 15, lg = lane >> 4;

  int bid = blockIdx.x;                     // 0..255
  int xcd = bid & 7, idx = bid >> 3;        // 32 blocks per XCD
  int r0 = (xcd * 32 + idx) * 32;           // 1024-row panel per XCD

  // ---- Phase 1: LN rows w*8 .. w*8+7 ----
#pragma unroll
  for (int rr = 0; rr < 8; ++rr) {
    int r = w * 8 + rr;
    const float* ar = attn + (size_t)(r0 + r) * DIM;
    float4 a = ((const float4*)ar)[lane * 2];
    float4 b = ((const float4*)ar)[lane * 2 + 1];
    float s = a.x + a.y + a.z + a.w + b.x + b.y + b.z + b.w;
#pragma unroll
    for (int o = 32; o; o >>= 1) s += __shfl_xor(s, o);
    float mu = s * (1.0f / DIM);
    float d[8] = {a.x - mu, a.y - mu, a.z - mu, a.w - mu,
                  b.x - mu, b.y - mu, b.z - mu, b.w - mu};
    float v = 0.f;
#pragma unroll
    for (int j = 0; j < 8; ++j) v += d[j] * d[j];
#pragma unroll
    for (int o = 32; o; o >>= 1) v += __shfl_xor(v, o);
    float rs = rsqrtf(v * (1.0f / DIM) + 1e-6f);
    u16x8 u8 = *(const u16x8*)(proj + (size_t)(r0 + r) * EDIM + lane * 8);
    u16x8 o8;
#pragma unroll
    for (int j = 0; j < 8; ++j) o8[j] = f2bf(bf2f(u8[j]) * (d[j] * rs));
    *(u16x8*)&os[r * 512 + ((lane * 8) ^ ((r & 7) << 3))] = o8;
  }
  __syncthreads();

  // ---- Phase 2: GEMM, wave w covers cols w*128..w*128+127 ----
  int cb = w * 128;
  f32x4 acc[2][8];
  f32x4 z = {0.f, 0.f, 0.f, 0.f};
#pragma unroll
  for (int mt = 0; mt < 2; ++mt)
#pragma unroll
    for (int nt = 0; nt < 8; ++nt) acc[mt][nt] = z;

#pragma unroll 2
  for (int kc = 0; kc < 16; ++kc) {
    bf16x8 af[2];
#pragma unroll
    for (int mt = 0; mt < 2; ++mt)
      af[mt] = ldb(&os[(mt * 16 + lm) * 512 +
                       ((kc * 32 + lg * 8) ^ ((lm & 7) << 3))]);
    bf16x8 bfr[8];
#pragma unroll
    for (int nt = 0; nt < 8; ++nt)
      bfr[nt] = ldb(Bw + (size_t)(cb + nt * 16 + lm) * DIM + kc * 32 + lg * 8);
#pragma unroll
    for (int mt = 0; mt < 2; ++mt)
#pragma unroll
      for (int nt = 0; nt < 8; ++nt)
        acc[mt][nt] = MFMA16(af[mt], bfr[nt], acc[mt][nt]);
  }

#pragma unroll
  for (int mt = 0; mt < 2; ++mt)
#pragma unroll
    for (int nt = 0; nt < 8; ++nt)
#pragma unroll
      for (int i = 0; i < 4; ++i) {
        size_t row = r0 + mt * 16 + lg * 4 + i;
        int col = cb + nt * 16 + lm;
        out[row * DIM + col] = acc[mt][nt][i] + o_b[col] + x[row * DIM + col];
      }
}

extern "C" void kernel_launch(void* const* d_in, const int* in_sizes, int n_in,
                              void* d_out, int out_size, void* d_ws, size_t ws_size,
                              hipStream_t stream) {
  const float* x    = (const float*)d_in[0];
  // d_in[1] = invalid_attn_mask: structurally causal tril; applied as predicate.
  const float* uvqk = (const float*)d_in[2];
  const float* o_w  = (const float*)d_in[3];
  const float* o_b  = (const float*)d_in[4];
  float* out = (float*)d_out;

  u16* uvqk_t = (u16*)d_ws;                         // [2048][512] bf16   2MB
  u16* ow_bf  = uvqk_t + (size_t)EDIM * DIM;        // [512][512]  bf16   0.5MB
  u16* xn     = ow_bf + (size_t)DIM * DIM;          // [8192][512] bf16   8MB
  u16* proj   = xn + (size_t)BNROWS * DIM;          // [8192][2048] bf16  32MB
  float* attn = (float*)(proj + (size_t)BNROWS * EDIM); // [8192][512] f32 16MB
  u16* o_in   = (u16*)(attn + (size_t)BNROWS * DIM);    // (unused now)   8MB
  u16* vt     = o_in + (size_t)BNROWS * DIM;            // [32][64][2048] bf16 8MB

  k_pre<<<dim3(3328), 256, 0, stream>>>(uvqk, o_w, x, uvqk_t, ow_bf, xn);
  k_gemm1<<<dim3(1024), 256, 0, stream>>>(xn, uvqk_t, proj, vt);
  k_attn<<<dim3(1024), 256, 0, stream>>>(proj, vt, attn);
  k_gemm2f<<<dim3(256), 256, 0, stream>>>(attn, proj, ow_bf, o_b, x, out);
}